// Round 4
// baseline (214.380 us; speedup 1.0000x reference)
//
#include <hip/hip_runtime.h>

#define DEV static __device__ __forceinline__

typedef __bf16 bf16x8 __attribute__((ext_vector_type(8)));
typedef __bf16 bf16x4 __attribute__((ext_vector_type(4)));
typedef float f32x4 __attribute__((ext_vector_type(4)));
typedef float f32x16 __attribute__((ext_vector_type(16)));
typedef unsigned int uint4v __attribute__((ext_vector_type(4)));
typedef unsigned short ushort4v __attribute__((ext_vector_type(4)));
using u16 = unsigned short;

#define NN 2048
#define DIMD 1024

DEV u16 f2bf(float f) {  // RNE via hardware cvt
    __bf16 b = (__bf16)f;
    return __builtin_bit_cast(u16, b);
}
DEV float bf2f(u16 s) {
    unsigned u = ((unsigned)s) << 16;
    return __builtin_bit_cast(float, u);
}
DEV bf16x8 load16(const u16* p) { return __builtin_bit_cast(bf16x8, *(const uint4v*)p); }
DEV f32x4 mfma16(bf16x8 a, bf16x8 b, f32x4 c) {
    return __builtin_amdgcn_mfma_f32_16x16x32_bf16(a, b, c, 0, 0, 0);
}
DEV f32x16 mfma32(bf16x8 a, bf16x8 b, f32x16 c) {
    return __builtin_amdgcn_mfma_f32_32x32x16_bf16(a, b, c, 0, 0, 0);
}
DEV float wredsum(float v) {
#pragma unroll
    for (int o = 32; o; o >>= 1) v += __shfl_xor(v, o);
    return v;
}
// async global->LDS, 16B per lane; lds base must be wave-uniform
DEV void gl_lds16(const u16* g, u16* l) {
    __builtin_amdgcn_global_load_lds((const __attribute__((address_space(1))) void*)g,
                                     (__attribute__((address_space(3))) void*)l, 16, 0, 0);
}

// ---------------- prep kernels ----------------

__global__ __launch_bounds__(256) void k_pack_x(const float* __restrict__ x,
                                                u16* __restrict__ xb, int n4) {
    int i = blockIdx.x * 256 + threadIdx.x;
    if (i >= n4) return;
    float4 v = ((const float4*)x)[i];
    ushort4v o;
    o[0] = f2bf(v.x); o[1] = f2bf(v.y); o[2] = f2bf(v.z); o[3] = f2bf(v.w);
    *(ushort4v*)(xb + (size_t)i * 4) = o;
}

// dst[n][k] = src[k][n], 1024x1024, fp32 -> bf16
__global__ __launch_bounds__(256) void k_transpose_w(const float* __restrict__ s0,
                                                     const float* __restrict__ s1,
                                                     const float* __restrict__ s2,
                                                     const float* __restrict__ s3,
                                                     u16* __restrict__ wqkv_t,
                                                     u16* __restrict__ wo_t) {
    __shared__ float tile[32][33];
    int z = blockIdx.z;
    const float* src = (z == 0) ? s0 : (z == 1) ? s1 : (z == 2) ? s2 : s3;
    u16* dst = (z < 3) ? (wqkv_t + (size_t)z * 1024 * 1024) : wo_t;
    int tx = threadIdx.x & 31, ty = threadIdx.x >> 5;  // ty 0..7
    int kb = blockIdx.y * 32, nb = blockIdx.x * 32;
#pragma unroll
    for (int j = 0; j < 4; ++j)
        tile[ty + 8 * j][tx] = src[(size_t)(kb + ty + 8 * j) * 1024 + nb + tx];
    __syncthreads();
#pragma unroll
    for (int j = 0; j < 4; ++j)
        dst[(size_t)(nb + ty + 8 * j) * 1024 + kb + tx] = f2bf(tile[tx][ty + 8 * j]);
}

__global__ __launch_bounds__(256) void k_pack_bias(const float* __restrict__ bq,
                                                   const float* __restrict__ bk,
                                                   const float* __restrict__ bv,
                                                   float* __restrict__ bqkv) {
    int i = blockIdx.x * 256 + threadIdx.x;
    if (i >= 3072) return;
    bqkv[i] = (i < 1024) ? bq[i] : (i < 2048) ? bk[i - 1024] : bv[i - 2048];
}

// ---------------- GEMM: C[m][n] = A[m][K] * Bt[n][K]^T, K=1024 ----------------
// m97 structure: global_load_lds width-16 into linear LDS, 128x128 tile, BK=32.
// MODE 0: out bf16 = acc + bias[n]          (ldc = Ncols)
// MODE 1: out fp32 = (acc + bias[n])*gamma[n]
template <int MODE>
__global__ __launch_bounds__(256) void k_gemm(const u16* __restrict__ A,
                                              const u16* __restrict__ Bt,
                                              const float* __restrict__ bias,
                                              const float* __restrict__ gamma,
                                              void* __restrict__ out, int ldc) {
    __shared__ u16 As[128 * 32];  // linear: row stride 32 elems (64B)
    __shared__ u16 Bs[128 * 32];
    const int K = 1024;
    const int m0 = blockIdx.x * 128, n0 = blockIdx.y * 128;
    const int tid = threadIdx.x;
    const int lane = tid & 63, w = tid >> 6;
    const int wr = w >> 1, wc = w & 1;
    const int li = lane & 15, g = lane >> 4;

    f32x4 acc[4][4] = {};

    // staging: wave w covers rows w*16 + lane/4 (and +64), 16B per lane
    const u16* gA = A + (size_t)(m0 + w * 16 + (lane >> 2)) * K + (lane & 3) * 8;
    const u16* gB = Bt + (size_t)(n0 + w * 16 + (lane >> 2)) * K + (lane & 3) * 8;
    u16* lA = &As[(w * 16) * 32];  // wave-uniform; HW adds lane*16B
    u16* lB = &Bs[(w * 16) * 32];

    for (int k0 = 0; k0 < K; k0 += 32) {
        __syncthreads();  // all reads of previous tile done
        gl_lds16(gA + k0, lA);
        gl_lds16(gA + (size_t)64 * K + k0, lA + 64 * 32);
        gl_lds16(gB + k0, lB);
        gl_lds16(gB + (size_t)64 * K + k0, lB + 64 * 32);
        asm volatile("s_waitcnt vmcnt(0)" ::: "memory");
        __syncthreads();  // tile visible
        bf16x8 af[4], bfv[4];
#pragma unroll
        for (int mi = 0; mi < 4; ++mi)
            af[mi] = load16(&As[(wr * 64 + mi * 16 + li) * 32 + g * 8]);
#pragma unroll
        for (int ni = 0; ni < 4; ++ni)
            bfv[ni] = load16(&Bs[(wc * 64 + ni * 16 + li) * 32 + g * 8]);
#pragma unroll
        for (int mi = 0; mi < 4; ++mi)
#pragma unroll
            for (int ni = 0; ni < 4; ++ni)
                acc[mi][ni] = mfma16(af[mi], bfv[ni], acc[mi][ni]);
    }

#pragma unroll
    for (int mi = 0; mi < 4; ++mi) {
        int row = m0 + wr * 64 + mi * 16 + 4 * g;  // C/D: row = 4*(lane>>4)+r
#pragma unroll
        for (int ni = 0; ni < 4; ++ni) {
            int col = n0 + wc * 64 + ni * 16 + li;  // C/D: col = lane&15
            float bv_ = bias[col];
            f32x4 v = acc[mi][ni];
            if (MODE == 0) {
                u16* o = (u16*)out;
#pragma unroll
                for (int r = 0; r < 4; ++r)
                    o[(size_t)(row + r) * ldc + col] = f2bf(v[r] + bv_);
            } else {
                float gv = gamma[col];
                float* o = (float*)out;
#pragma unroll
                for (int r = 0; r < 4; ++r)
                    o[(size_t)(row + r) * ldc + col] = (v[r] + bv_) * gv;
            }
        }
    }
}

// ---------------- LayerNorm(q,k over D=64) + repack, V transpose ----------------
// qkv: [4096][3072] bf16 (q|k|v). Out: Qn,Kn [bh][n][64] bf16; Vt [bh][64][N] bf16.
__global__ __launch_bounds__(256) void k_ln_repack(const u16* __restrict__ qkv,
                                                   const float* __restrict__ qs,
                                                   const float* __restrict__ qb,
                                                   const float* __restrict__ ks,
                                                   const float* __restrict__ kb,
                                                   u16* __restrict__ Qn,
                                                   u16* __restrict__ Kn,
                                                   u16* __restrict__ Vt) {
    __shared__ u16 vtile[64][72];
    const int bh = blockIdx.y, b = bh >> 4, h = bh & 15;
    const int n0 = blockIdx.x * 64;
    const int tid = threadIdx.x;
    const int wv = tid >> 6, lane = tid & 63;  // lane == d
    const float qsv = qs[lane], qbv = qb[lane], ksv = ks[lane], kbv = kb[lane];
    for (int rr = 0; rr < 16; ++rr) {
        const int nl = wv * 16 + rr;
        const int n = n0 + nl;
        const size_t base = (size_t)(b * NN + n) * 3072 + h * 64 + lane;
        float qf = bf2f(qkv[base]);
        float kf = bf2f(qkv[base + 1024]);
        float vf = bf2f(qkv[base + 2048]);
        float mq = wredsum(qf) * (1.0f / 64.0f);
        float dq = qf - mq;
        float vq = wredsum(dq * dq) * (1.0f / 64.0f);
        Qn[((size_t)bh * NN + n) * 64 + lane] = f2bf(dq * rsqrtf(vq + 1e-6f) * qsv + qbv);
        float mk = wredsum(kf) * (1.0f / 64.0f);
        float dk = kf - mk;
        float vk = wredsum(dk * dk) * (1.0f / 64.0f);
        Kn[((size_t)bh * NN + n) * 64 + lane] = f2bf(dk * rsqrtf(vk + 1e-6f) * ksv + kbv);
        vtile[nl][lane] = f2bf(vf);
    }
    __syncthreads();
    const int d = tid >> 2, c = tid & 3;
    alignas(16) u16 tmp[16];
#pragma unroll
    for (int k2 = 0; k2 < 16; ++k2) tmp[k2] = vtile[16 * c + k2][d];
    const size_t vbase = ((size_t)bh * 64 + d) * NN + n0 + 16 * c;
    *(uint4v*)(Vt + vbase) = *(const uint4v*)&tmp[0];
    *(uint4v*)(Vt + vbase + 8) = *(const uint4v*)&tmp[8];
}

// ---------------- fused sigmoid attention v4 ----------------
// Block = 32 queries x 4 waves; wave jq owns a 512-key j-quarter. Barrier-free
// j-loop, step 64 (two independent 32-key sub-tiles per body for ILP).
// In-register P via cvt_pk_bf16 + permlane32_swap (T12). Cross-wave combine
// once at the end via pad-65 f32 LDS tree. XCD swizzle: 4 bh per XCD.
__global__ __launch_bounds__(256) void k_attn(const u16* __restrict__ Qn,
                                              const u16* __restrict__ Kn,
                                              const u16* __restrict__ Vt,
                                              const float* __restrict__ ib,
                                              u16* __restrict__ attn_out) {
    __shared__ float red[2][32][65];  // 16.6 KB, conflict-free (stride 65)
    const int bid = blockIdx.x;
    const int xcd = bid & 7, idx = bid >> 3;  // 2048 blocks: 256 per XCD
    const int bh = xcd * 4 + (idx >> 6);      // 4 bh per XCD -> K/V L2-resident
    const int iblk = idx & 63;
    const int b = bh >> 4, h = bh & 15;
    const int tid = threadIdx.x;
    const int jq = tid >> 6, lane = tid & 63;
    const int l32 = lane & 31, hi = lane >> 5;
    const int i0 = iblk * 32;
    const float nbias = -ib[0];
    const u16* Qb = Qn + (size_t)bh * NN * 64;
    const u16* Kb = Kn + (size_t)bh * NN * 64 + (size_t)(jq * 512) * 64;
    const u16* Vb = Vt + (size_t)bh * 64 * NN + jq * 512;

    // Q fragments (B-operand of S^T): Q[i0+l32][16s+8hi..+8], hoisted
    bf16x8 qf[4];
#pragma unroll
    for (int s = 0; s < 4; ++s)
        qf[s] = load16(Qb + (size_t)(i0 + l32) * 64 + 16 * s + 8 * hi);

    f32x16 accO[2] = {f32x16{}, f32x16{}};

    for (int j0 = 0; j0 < 512; j0 += 64) {
        // K fragments for both 32-key sub-tiles
        bf16x8 kfA[4], kfB[4];
#pragma unroll
        for (int s = 0; s < 4; ++s)
            kfA[s] = load16(Kb + (size_t)(j0 + l32) * 64 + 16 * s + 8 * hi);
#pragma unroll
        for (int s = 0; s < 4; ++s)
            kfB[s] = load16(Kb + (size_t)(j0 + 32 + l32) * 64 + 16 * s + 8 * hi);
        // QK^T: two independent accumulate chains
        __builtin_amdgcn_s_setprio(1);
        f32x16 saA = {}, saB = {};
#pragma unroll
        for (int s = 0; s < 4; ++s) saA = mfma32(kfA[s], qf[s], saA);
#pragma unroll
        for (int s = 0; s < 4; ++s) saB = mfma32(kfB[s], qf[s], saB);
        __builtin_amdgcn_s_setprio(0);
        // V fragments issued here: L2 latency hides under the sigmoid block
        bf16x8 vfA[2][2], vfB[2][2];
#pragma unroll
        for (int db = 0; db < 2; ++db)
#pragma unroll
            for (int js = 0; js < 2; ++js) {
                vfA[db][js] =
                    load16(Vb + (size_t)(db * 32 + l32) * NN + j0 + js * 16 + 8 * hi);
                vfB[db][js] =
                    load16(Vb + (size_t)(db * 32 + l32) * NN + j0 + 32 + js * 16 + 8 * hi);
            }
        // sigmoid (lane holds j = (r&3)+8(r>>2)+4hi, query col i = l32)
        float pA[16], pB[16];
#pragma unroll
        for (int r = 0; r < 16; ++r) {
            pA[r] = __builtin_amdgcn_rcpf(1.0f + __expf(nbias - saA[r]));
            pB[r] = __builtin_amdgcn_rcpf(1.0f + __expf(nbias - saB[r]));
        }
        // pack to bf16 B-fragments via cvt_pk + permlane32_swap (T12)
        unsigned wdA[8], wdB[8];
#pragma unroll
        for (int t = 0; t < 8; ++t) {
            unsigned rA, rB;
            asm("v_cvt_pk_bf16_f32 %0, %1, %2" : "=v"(rA) : "v"(pA[2 * t]), "v"(pA[2 * t + 1]));
            asm("v_cvt_pk_bf16_f32 %0, %1, %2" : "=v"(rB) : "v"(pB[2 * t]), "v"(pB[2 * t + 1]));
            wdA[t] = rA; wdB[t] = rB;
        }
        asm("v_permlane32_swap_b32 %0, %1" : "+v"(wdA[0]), "+v"(wdA[2]));
        asm("v_permlane32_swap_b32 %0, %1" : "+v"(wdA[1]), "+v"(wdA[3]));
        asm("v_permlane32_swap_b32 %0, %1" : "+v"(wdA[4]), "+v"(wdA[6]));
        asm("v_permlane32_swap_b32 %0, %1" : "+v"(wdA[5]), "+v"(wdA[7]));
        asm("v_permlane32_swap_b32 %0, %1" : "+v"(wdB[0]), "+v"(wdB[2]));
        asm("v_permlane32_swap_b32 %0, %1" : "+v"(wdB[1]), "+v"(wdB[3]));
        asm("v_permlane32_swap_b32 %0, %1" : "+v"(wdB[4]), "+v"(wdB[6]));
        asm("v_permlane32_swap_b32 %0, %1" : "+v"(wdB[5]), "+v"(wdB[7]));
        uint4v uA0 = {wdA[0], wdA[1], wdA[2], wdA[3]};
        uint4v uA1 = {wdA[4], wdA[5], wdA[6], wdA[7]};
        uint4v uB0 = {wdB[0], wdB[1], wdB[2], wdB[3]};
        uint4v uB1 = {wdB[4], wdB[5], wdB[6], wdB[7]};
        bf16x8 pA0 = __builtin_bit_cast(bf16x8, uA0);
        bf16x8 pA1 = __builtin_bit_cast(bf16x8, uA1);
        bf16x8 pB0 = __builtin_bit_cast(bf16x8, uB0);
        bf16x8 pB1 = __builtin_bit_cast(bf16x8, uB1);
        // PV: O^T += V^T.P^T (accumulate chains pipeline at full rate)
        __builtin_amdgcn_s_setprio(1);
        accO[0] = mfma32(vfA[0][0], pA0, accO[0]);
        accO[0] = mfma32(vfA[0][1], pA1, accO[0]);
        accO[1] = mfma32(vfA[1][0], pA0, accO[1]);
        accO[1] = mfma32(vfA[1][1], pA1, accO[1]);
        accO[0] = mfma32(vfB[0][0], pB0, accO[0]);
        accO[0] = mfma32(vfB[0][1], pB1, accO[0]);
        accO[1] = mfma32(vfB[1][0], pB0, accO[1]);
        accO[1] = mfma32(vfB[1][1], pB1, accO[1]);
        __builtin_amdgcn_s_setprio(0);
    }

    // cross-wave combine: jq1->red0, jq3->red1; jq0+=red0, jq2+=red1;
    // jq2->red0; jq0+=red0; jq0 stores.
    if (jq & 1) {
#pragma unroll
        for (int db = 0; db < 2; ++db)
#pragma unroll
            for (int r = 0; r < 16; ++r)
                red[jq >> 1][l32][db * 32 + (r & 3) + 8 * (r >> 2) + 4 * hi] = accO[db][r];
    }
    __syncthreads();
    if (!(jq & 1)) {
#pragma unroll
        for (int db = 0; db < 2; ++db)
#pragma unroll
            for (int r = 0; r < 16; ++r)
                accO[db][r] += red[jq >> 1][l32][db * 32 + (r & 3) + 8 * (r >> 2) + 4 * hi];
    }
    __syncthreads();
    if (jq == 2) {
#pragma unroll
        for (int db = 0; db < 2; ++db)
#pragma unroll
            for (int r = 0; r < 16; ++r)
                red[0][l32][db * 32 + (r & 3) + 8 * (r >> 2) + 4 * hi] = accO[db][r];
    }
    __syncthreads();
    if (jq == 0) {
#pragma unroll
        for (int db = 0; db < 2; ++db)
#pragma unroll
            for (int r = 0; r < 16; ++r)
                accO[db][r] += red[0][l32][db * 32 + (r & 3) + 8 * (r >> 2) + 4 * hi];
        const int i = i0 + l32;
#pragma unroll
        for (int db = 0; db < 2; ++db)
#pragma unroll
            for (int q = 0; q < 4; ++q) {
                int d = db * 32 + 8 * q + 4 * hi;
                bf16x4 o4;
#pragma unroll
                for (int r = 0; r < 4; ++r) o4[r] = (__bf16)accO[db][4 * q + r];
                *(bf16x4*)&attn_out[(size_t)(b * NN + i) * 1024 + h * 64 + d] = o4;
            }
    }
}

// ---------------- launch ----------------

extern "C" void kernel_launch(void* const* d_in, const int* in_sizes, int n_in,
                              void* d_out, int out_size, void* d_ws, size_t ws_size,
                              hipStream_t stream) {
    (void)in_sizes; (void)n_in; (void)out_size; (void)ws_size;
    const float* x     = (const float*)d_in[0];
    const float* Wq    = (const float*)d_in[1];
    const float* bq    = (const float*)d_in[2];
    const float* Wk    = (const float*)d_in[3];
    const float* bk    = (const float*)d_in[4];
    const float* Wv    = (const float*)d_in[5];
    const float* bv    = (const float*)d_in[6];
    const float* qn_s  = (const float*)d_in[7];
    const float* qn_b  = (const float*)d_in[8];
    const float* kn_s  = (const float*)d_in[9];
    const float* kn_b  = (const float*)d_in[10];
    const float* ib    = (const float*)d_in[11];
    const float* Wo    = (const float*)d_in[12];
    const float* bo    = (const float*)d_in[13];
    const float* gamma = (const float*)d_in[14];
    float* out = (float*)d_out;

    char* ws = (char*)d_ws;
    size_t off = 0;
    auto alloc = [&](size_t bytes) -> void* {
        void* p = ws + off;
        off += (bytes + 255) & ~(size_t)255;
        return p;
    };
    u16* xb       = (u16*)alloc((size_t)4096 * 1024 * 2);   // x bf16
    u16* wqkv_t   = (u16*)alloc((size_t)3072 * 1024 * 2);   // [n][k]
    u16* wo_t     = (u16*)alloc((size_t)1024 * 1024 * 2);
    float* bqkv   = (float*)alloc((size_t)3072 * 4);
    u16* qkv_raw  = (u16*)alloc((size_t)4096 * 3072 * 2);   // q|k|v rows
    u16* Qn       = (u16*)alloc((size_t)32 * 2048 * 64 * 2);
    u16* Kn       = (u16*)alloc((size_t)32 * 2048 * 64 * 2);
    u16* Vtp      = (u16*)alloc((size_t)32 * 64 * 2048 * 2);
    u16* attn_out = (u16*)alloc((size_t)4096 * 1024 * 2);

    k_pack_x<<<4096, 256, 0, stream>>>(x, xb, 1048576);
    k_transpose_w<<<dim3(32, 32, 4), 256, 0, stream>>>(Wq, Wk, Wv, Wo, wqkv_t, wo_t);
    k_pack_bias<<<12, 256, 0, stream>>>(bq, bk, bv, bqkv);
    k_gemm<0><<<dim3(32, 24), 256, 0, stream>>>(xb, wqkv_t, bqkv, nullptr, qkv_raw, 3072);
    k_ln_repack<<<dim3(32, 32), 256, 0, stream>>>(qkv_raw, qn_s, qn_b, kn_s, kn_b, Qn, Kn, Vtp);
    k_attn<<<2048, 256, 0, stream>>>(Qn, Kn, Vtp, ib, attn_out);
    k_gemm<1><<<dim3(32, 8), 256, 0, stream>>>(attn_out, wo_t, bo, gamma, out, 1024);
}

// Round 5
// 144.136 us; speedup vs baseline: 1.4873x; 1.4873x over previous
//
#include <hip/hip_runtime.h>

#define DEV static __device__ __forceinline__

typedef __bf16 bf16x8 __attribute__((ext_vector_type(8)));
typedef __bf16 bf16x4 __attribute__((ext_vector_type(4)));
typedef float f32x4 __attribute__((ext_vector_type(4)));
typedef float f32x16 __attribute__((ext_vector_type(16)));
typedef unsigned int uint4v __attribute__((ext_vector_type(4)));
typedef unsigned short ushort4v __attribute__((ext_vector_type(4)));
using u16 = unsigned short;

#define NN 2048
#define DIMD 1024

DEV u16 f2bf(float f) {  // RNE via hardware cvt
    __bf16 b = (__bf16)f;
    return __builtin_bit_cast(u16, b);
}
DEV float bf2f(u16 s) {
    unsigned u = ((unsigned)s) << 16;
    return __builtin_bit_cast(float, u);
}
DEV bf16x8 load16(const u16* p) { return __builtin_bit_cast(bf16x8, *(const uint4v*)p); }
DEV f32x4 mfma16(bf16x8 a, bf16x8 b, f32x4 c) {
    return __builtin_amdgcn_mfma_f32_16x16x32_bf16(a, b, c, 0, 0, 0);
}
DEV f32x16 mfma32(bf16x8 a, bf16x8 b, f32x16 c) {
    return __builtin_amdgcn_mfma_f32_32x32x16_bf16(a, b, c, 0, 0, 0);
}
DEV float wredsum(float v) {
#pragma unroll
    for (int o = 32; o; o >>= 1) v += __shfl_xor(v, o);
    return v;
}
// async global->LDS, 16B per lane; lds base must be wave-uniform
DEV void gl_lds16(const u16* g, u16* l) {
    __builtin_amdgcn_global_load_lds((const __attribute__((address_space(1))) void*)g,
                                     (__attribute__((address_space(3))) void*)l, 16, 0, 0);
}

// ---------------- prep kernels ----------------

__global__ __launch_bounds__(256) void k_pack_x(const float* __restrict__ x,
                                                u16* __restrict__ xb, int n4) {
    int i = blockIdx.x * 256 + threadIdx.x;
    if (i >= n4) return;
    float4 v = ((const float4*)x)[i];
    ushort4v o;
    o[0] = f2bf(v.x); o[1] = f2bf(v.y); o[2] = f2bf(v.z); o[3] = f2bf(v.w);
    *(ushort4v*)(xb + (size_t)i * 4) = o;
}

// dst[n][k] = src[k][n], 1024x1024, fp32 -> bf16
__global__ __launch_bounds__(256) void k_transpose_w(const float* __restrict__ s0,
                                                     const float* __restrict__ s1,
                                                     const float* __restrict__ s2,
                                                     const float* __restrict__ s3,
                                                     u16* __restrict__ wqkv_t,
                                                     u16* __restrict__ wo_t) {
    __shared__ float tile[32][33];
    int z = blockIdx.z;
    const float* src = (z == 0) ? s0 : (z == 1) ? s1 : (z == 2) ? s2 : s3;
    u16* dst = (z < 3) ? (wqkv_t + (size_t)z * 1024 * 1024) : wo_t;
    int tx = threadIdx.x & 31, ty = threadIdx.x >> 5;  // ty 0..7
    int kb = blockIdx.y * 32, nb = blockIdx.x * 32;
#pragma unroll
    for (int j = 0; j < 4; ++j)
        tile[ty + 8 * j][tx] = src[(size_t)(kb + ty + 8 * j) * 1024 + nb + tx];
    __syncthreads();
#pragma unroll
    for (int j = 0; j < 4; ++j)
        dst[(size_t)(nb + ty + 8 * j) * 1024 + kb + tx] = f2bf(tile[tx][ty + 8 * j]);
}

__global__ __launch_bounds__(256) void k_pack_bias(const float* __restrict__ bq,
                                                   const float* __restrict__ bk,
                                                   const float* __restrict__ bv,
                                                   float* __restrict__ bqkv) {
    int i = blockIdx.x * 256 + threadIdx.x;
    if (i >= 3072) return;
    bqkv[i] = (i < 1024) ? bq[i] : (i < 2048) ? bk[i - 1024] : bv[i - 2048];
}

// ---------------- GEMM: C[m][n] = A[m][K] * Bt[n][K]^T, K=1024 ----------------
// m97 structure: global_load_lds width-16 into linear LDS, 128x128 tile, BK=32.
// MODE 0: out bf16 = acc + bias[n]          (ldc = Ncols)
// MODE 1: out fp32 = (acc + bias[n])*gamma[n]
template <int MODE>
__global__ __launch_bounds__(256) void k_gemm(const u16* __restrict__ A,
                                              const u16* __restrict__ Bt,
                                              const float* __restrict__ bias,
                                              const float* __restrict__ gamma,
                                              void* __restrict__ out, int ldc) {
    __shared__ u16 As[128 * 32];  // linear: row stride 32 elems (64B)
    __shared__ u16 Bs[128 * 32];
    const int K = 1024;
    const int m0 = blockIdx.x * 128, n0 = blockIdx.y * 128;
    const int tid = threadIdx.x;
    const int lane = tid & 63, w = tid >> 6;
    const int wr = w >> 1, wc = w & 1;
    const int li = lane & 15, g = lane >> 4;

    f32x4 acc[4][4] = {};

    // staging: wave w covers rows w*16 + lane/4 (and +64), 16B per lane
    const u16* gA = A + (size_t)(m0 + w * 16 + (lane >> 2)) * K + (lane & 3) * 8;
    const u16* gB = Bt + (size_t)(n0 + w * 16 + (lane >> 2)) * K + (lane & 3) * 8;
    u16* lA = &As[(w * 16) * 32];  // wave-uniform; HW adds lane*16B
    u16* lB = &Bs[(w * 16) * 32];

    for (int k0 = 0; k0 < K; k0 += 32) {
        __syncthreads();  // all reads of previous tile done
        gl_lds16(gA + k0, lA);
        gl_lds16(gA + (size_t)64 * K + k0, lA + 64 * 32);
        gl_lds16(gB + k0, lB);
        gl_lds16(gB + (size_t)64 * K + k0, lB + 64 * 32);
        asm volatile("s_waitcnt vmcnt(0)" ::: "memory");
        __syncthreads();  // tile visible
        bf16x8 af[4], bfv[4];
#pragma unroll
        for (int mi = 0; mi < 4; ++mi)
            af[mi] = load16(&As[(wr * 64 + mi * 16 + li) * 32 + g * 8]);
#pragma unroll
        for (int ni = 0; ni < 4; ++ni)
            bfv[ni] = load16(&Bs[(wc * 64 + ni * 16 + li) * 32 + g * 8]);
#pragma unroll
        for (int mi = 0; mi < 4; ++mi)
#pragma unroll
            for (int ni = 0; ni < 4; ++ni)
                acc[mi][ni] = mfma16(af[mi], bfv[ni], acc[mi][ni]);
    }

#pragma unroll
    for (int mi = 0; mi < 4; ++mi) {
        int row = m0 + wr * 64 + mi * 16 + 4 * g;  // C/D: row = 4*(lane>>4)+r
#pragma unroll
        for (int ni = 0; ni < 4; ++ni) {
            int col = n0 + wc * 64 + ni * 16 + li;  // C/D: col = lane&15
            float bv_ = bias[col];
            f32x4 v = acc[mi][ni];
            if (MODE == 0) {
                u16* o = (u16*)out;
#pragma unroll
                for (int r = 0; r < 4; ++r)
                    o[(size_t)(row + r) * ldc + col] = f2bf(v[r] + bv_);
            } else {
                float gv = gamma[col];
                float* o = (float*)out;
#pragma unroll
                for (int r = 0; r < 4; ++r)
                    o[(size_t)(row + r) * ldc + col] = (v[r] + bv_) * gv;
            }
        }
    }
}

// ---------------- LayerNorm(q,k over D=64) + repack into MFMA-fragment-linear ----------------
// qkv: [4096][3072] bf16 (q|k|v). Outputs (per bh, 131072 u16 each):
//   Qf/Kf: slot ((tile*4 + s)*64 + hi*32 + row32)*8 + e  holds X[row][16s+8hi+e]
//   Vf:    slot ((jt*4 + db*2 + js)*64 + hi*32 + d32)*8 + e holds V[jt*32+js*16+8hi+e][db*32+d32]
// => attention fragment loads become base + (frag*64 + lane)*8: fully coalesced.
__global__ __launch_bounds__(256) void k_ln_repack(const u16* __restrict__ qkv,
                                                   const float* __restrict__ qs,
                                                   const float* __restrict__ qb,
                                                   const float* __restrict__ ks,
                                                   const float* __restrict__ kb,
                                                   u16* __restrict__ Qf,
                                                   u16* __restrict__ Kf,
                                                   u16* __restrict__ Vf) {
    __shared__ u16 vtile[64][72];
    const int bh = blockIdx.y, b = bh >> 4, h = bh & 15;
    const int n0 = blockIdx.x * 64;
    const int tid = threadIdx.x;
    const int wv = tid >> 6, lane = tid & 63;  // lane == d
    const float qsv = qs[lane], qbv = qb[lane], ksv = ks[lane], kbv = kb[lane];
    const int sL = lane >> 4, hiL = (lane >> 3) & 1, eL = lane & 7;
    u16* Qb_ = Qf + (size_t)bh * 131072;
    u16* Kb_ = Kf + (size_t)bh * 131072;
    for (int rr = 0; rr < 16; ++rr) {
        const int nl = wv * 16 + rr;
        const int n = n0 + nl;
        const size_t base = (size_t)(b * NN + n) * 3072 + h * 64 + lane;
        float qv = bf2f(qkv[base]);
        float kv = bf2f(qkv[base + 1024]);
        float vv = bf2f(qkv[base + 2048]);
        float mq = wredsum(qv) * (1.0f / 64.0f);
        float dq = qv - mq;
        float vq = wredsum(dq * dq) * (1.0f / 64.0f);
        float qn = dq * rsqrtf(vq + 1e-6f) * qsv + qbv;
        float mk = wredsum(kv) * (1.0f / 64.0f);
        float dk = kv - mk;
        float vk = wredsum(dk * dk) * (1.0f / 64.0f);
        float kn = dk * rsqrtf(vk + 1e-6f) * ksv + kbv;
        const size_t fo = ((size_t)((n >> 5) * 4 + sL)) * 512 + (hiL * 32 + (n & 31)) * 8 + eL;
        Qb_[fo] = f2bf(qn);
        Kb_[fo] = f2bf(kn);
        vtile[nl][lane] = f2bf(vv);
    }
    __syncthreads();
    const int d = tid >> 2, c = tid & 3;
    alignas(16) u16 tmp[16];
#pragma unroll
    for (int k2 = 0; k2 < 16; ++k2) tmp[k2] = vtile[16 * c + k2][d];
    const int jt = (n0 >> 5) + (c >> 1), js = c & 1, db = d >> 5, d32 = d & 31;
    u16* vb = Vf + (size_t)bh * 131072 + ((size_t)(jt * 4 + db * 2 + js)) * 512 + d32 * 8;
    *(uint4v*)vb = *(const uint4v*)&tmp[0];         // hi=0 chunk
    *(uint4v*)(vb + 256) = *(const uint4v*)&tmp[8]; // hi=1 chunk
}

// ---------------- fused sigmoid attention v5 ----------------
// Fragment-linear inputs: every load is lane-contiguous (8 lines/instr).
// Block = 64 queries x 4 waves; wave jq owns a 512-key j-quarter and BOTH
// 32-query i-tiles (K/V fragments reused in registers -> L2 traffic halved).
// Barrier-free j-loop; in-register P (cvt_pk + permlane32_swap); final
// cross-wave combine via pad-65 LDS tree. XCD swizzle: 4 bh per XCD.
__global__ __launch_bounds__(256, 2) void k_attn(const u16* __restrict__ Qf,
                                                 const u16* __restrict__ Kf,
                                                 const u16* __restrict__ Vf,
                                                 const float* __restrict__ ib,
                                                 u16* __restrict__ attn_out) {
    __shared__ float red[2][64][65];  // 33.3 KB
    const int bid = blockIdx.x;
    const int xcd = bid & 7, idx = bid >> 3;  // 1024 blocks: 128 per XCD
    const int bh = xcd * 4 + (idx >> 5);      // 4 bh per XCD -> K/V L2-resident
    const int iblk = idx & 31;
    const int b = bh >> 4, h = bh & 15;
    const int tid = threadIdx.x;
    const int jq = tid >> 6, lane = tid & 63;
    const int l32 = lane & 31, hi = lane >> 5;
    const float nbias = -ib[0];
    const u16* Qb = Qf + (size_t)bh * 131072;
    const u16* Kb = Kf + (size_t)bh * 131072;
    const u16* Vb = Vf + (size_t)bh * 131072;
    const int it0 = iblk * 2;

    // Q fragments for both i-tiles (coalesced), hoisted
    bf16x8 qf[2][4];
#pragma unroll
    for (int t = 0; t < 2; ++t)
#pragma unroll
        for (int s = 0; s < 4; ++s)
            qf[t][s] = load16(Qb + ((size_t)((it0 + t) * 4 + s)) * 512 + lane * 8);

    f32x16 accO[2][2] = {};
    const int jt0 = jq * 16;

    for (int jt = jt0; jt < jt0 + 16; ++jt) {
        const u16* kb = Kb + (size_t)jt * 2048;
        const u16* vb = Vb + (size_t)jt * 2048;
        bf16x8 kf[4], vf[2][2];
#pragma unroll
        for (int s = 0; s < 4; ++s) kf[s] = load16(kb + s * 512 + lane * 8);
#pragma unroll
        for (int db = 0; db < 2; ++db)
#pragma unroll
            for (int js = 0; js < 2; ++js)
                vf[db][js] = load16(vb + (db * 2 + js) * 512 + lane * 8);
        // per i-tile: QK^T then sigmoid+pack (T12)
        bf16x8 pb[2][2];
#pragma unroll
        for (int t = 0; t < 2; ++t) {
            __builtin_amdgcn_s_setprio(1);
            f32x16 sa = {};
#pragma unroll
            for (int s = 0; s < 4; ++s) sa = mfma32(kf[s], qf[t][s], sa);
            __builtin_amdgcn_s_setprio(0);
            float p[16];
#pragma unroll
            for (int r = 0; r < 16; ++r)
                p[r] = __builtin_amdgcn_rcpf(1.0f + __expf(nbias - sa[r]));
            unsigned wd[8];
#pragma unroll
            for (int u = 0; u < 8; ++u) {
                unsigned r_;
                asm("v_cvt_pk_bf16_f32 %0, %1, %2"
                    : "=v"(r_) : "v"(p[2 * u]), "v"(p[2 * u + 1]));
                wd[u] = r_;
            }
            asm("v_permlane32_swap_b32 %0, %1" : "+v"(wd[0]), "+v"(wd[2]));
            asm("v_permlane32_swap_b32 %0, %1" : "+v"(wd[1]), "+v"(wd[3]));
            asm("v_permlane32_swap_b32 %0, %1" : "+v"(wd[4]), "+v"(wd[6]));
            asm("v_permlane32_swap_b32 %0, %1" : "+v"(wd[5]), "+v"(wd[7]));
            uint4v u0 = {wd[0], wd[1], wd[2], wd[3]};
            uint4v u1 = {wd[4], wd[5], wd[6], wd[7]};
            pb[t][0] = __builtin_bit_cast(bf16x8, u0);  // keys [jt*32, +16)
            pb[t][1] = __builtin_bit_cast(bf16x8, u1);  // keys [jt*32+16, +16)
        }
        // PV: 8 MFMAs, 4 independent accumulate chains
        __builtin_amdgcn_s_setprio(1);
#pragma unroll
        for (int t = 0; t < 2; ++t)
#pragma unroll
            for (int db = 0; db < 2; ++db)
#pragma unroll
                for (int js = 0; js < 2; ++js)
                    accO[t][db] = mfma32(vf[db][js], pb[t][js], accO[t][db]);
        __builtin_amdgcn_s_setprio(0);
    }

    // cross-wave combine: jq1->red0, jq3->red1; jq0+=red0, jq2+=red1;
    // jq2->red0; jq0+=red0; jq0 stores.  (d = db*32 + (r&3)+8(r>>2)+4hi)
    if (jq & 1) {
#pragma unroll
        for (int t = 0; t < 2; ++t)
#pragma unroll
            for (int db = 0; db < 2; ++db)
#pragma unroll
                for (int r = 0; r < 16; ++r)
                    red[jq >> 1][t * 32 + l32][db * 32 + (r & 3) + 8 * (r >> 2) + 4 * hi] =
                        accO[t][db][r];
    }
    __syncthreads();
    if (!(jq & 1)) {
#pragma unroll
        for (int t = 0; t < 2; ++t)
#pragma unroll
            for (int db = 0; db < 2; ++db)
#pragma unroll
                for (int r = 0; r < 16; ++r)
                    accO[t][db][r] +=
                        red[jq >> 1][t * 32 + l32][db * 32 + (r & 3) + 8 * (r >> 2) + 4 * hi];
    }
    __syncthreads();
    if (jq == 2) {
#pragma unroll
        for (int t = 0; t < 2; ++t)
#pragma unroll
            for (int db = 0; db < 2; ++db)
#pragma unroll
                for (int r = 0; r < 16; ++r)
                    red[0][t * 32 + l32][db * 32 + (r & 3) + 8 * (r >> 2) + 4 * hi] =
                        accO[t][db][r];
    }
    __syncthreads();
    if (jq == 0) {
#pragma unroll
        for (int t = 0; t < 2; ++t)
#pragma unroll
            for (int db = 0; db < 2; ++db)
#pragma unroll
                for (int r = 0; r < 16; ++r)
                    accO[t][db][r] +=
                        red[0][t * 32 + l32][db * 32 + (r & 3) + 8 * (r >> 2) + 4 * hi];
        // epilogue: O^T C/D -> attn_out[(b*N + i)][h*64 + d] bf16
#pragma unroll
        for (int t = 0; t < 2; ++t) {
            const int i = it0 * 32 + t * 32 + l32;
#pragma unroll
            for (int db = 0; db < 2; ++db)
#pragma unroll
                for (int q = 0; q < 4; ++q) {
                    int d = db * 32 + 8 * q + 4 * hi;
                    bf16x4 o4;
#pragma unroll
                    for (int r = 0; r < 4; ++r) o4[r] = (__bf16)accO[t][db][4 * q + r];
                    *(bf16x4*)&attn_out[(size_t)(b * NN + i) * 1024 + h * 64 + d] = o4;
                }
        }
    }
}

// ---------------- launch ----------------

extern "C" void kernel_launch(void* const* d_in, const int* in_sizes, int n_in,
                              void* d_out, int out_size, void* d_ws, size_t ws_size,
                              hipStream_t stream) {
    (void)in_sizes; (void)n_in; (void)out_size; (void)ws_size;
    const float* x     = (const float*)d_in[0];
    const float* Wq    = (const float*)d_in[1];
    const float* bq    = (const float*)d_in[2];
    const float* Wk    = (const float*)d_in[3];
    const float* bk    = (const float*)d_in[4];
    const float* Wv    = (const float*)d_in[5];
    const float* bv    = (const float*)d_in[6];
    const float* qn_s  = (const float*)d_in[7];
    const float* qn_b  = (const float*)d_in[8];
    const float* kn_s  = (const float*)d_in[9];
    const float* kn_b  = (const float*)d_in[10];
    const float* ib    = (const float*)d_in[11];
    const float* Wo    = (const float*)d_in[12];
    const float* bo    = (const float*)d_in[13];
    const float* gamma = (const float*)d_in[14];
    float* out = (float*)d_out;

    char* ws = (char*)d_ws;
    size_t off = 0;
    auto alloc = [&](size_t bytes) -> void* {
        void* p = ws + off;
        off += (bytes + 255) & ~(size_t)255;
        return p;
    };
    u16* xb       = (u16*)alloc((size_t)4096 * 1024 * 2);   // x bf16
    u16* wqkv_t   = (u16*)alloc((size_t)3072 * 1024 * 2);   // [n][k]
    u16* wo_t     = (u16*)alloc((size_t)1024 * 1024 * 2);
    float* bqkv   = (float*)alloc((size_t)3072 * 4);
    u16* qkv_raw  = (u16*)alloc((size_t)4096 * 3072 * 2);   // q|k|v rows
    u16* Qf       = (u16*)alloc((size_t)32 * 131072 * 2);   // fragment-linear
    u16* Kf       = (u16*)alloc((size_t)32 * 131072 * 2);
    u16* Vf       = (u16*)alloc((size_t)32 * 131072 * 2);
    u16* attn_out = (u16*)alloc((size_t)4096 * 1024 * 2);

    k_pack_x<<<4096, 256, 0, stream>>>(x, xb, 1048576);
    k_transpose_w<<<dim3(32, 32, 4), 256, 0, stream>>>(Wq, Wk, Wv, Wo, wqkv_t, wo_t);
    k_pack_bias<<<12, 256, 0, stream>>>(bq, bk, bv, bqkv);
    k_gemm<0><<<dim3(32, 24), 256, 0, stream>>>(xb, wqkv_t, bqkv, nullptr, qkv_raw, 3072);
    k_ln_repack<<<dim3(32, 32), 256, 0, stream>>>(qkv_raw, qn_s, qn_b, kn_s, kn_b, Qf, Kf, Vf);
    k_attn<<<1024, 256, 0, stream>>>(Qf, Kf, Vf, ib, attn_out);
    k_gemm<1><<<dim3(32, 8), 256, 0, stream>>>(attn_out, wo_t, bo, gamma, out, 1024);
}

// Round 6
// 131.381 us; speedup vs baseline: 1.6317x; 1.0971x over previous
//
#include <hip/hip_runtime.h>

#define DEV static __device__ __forceinline__

typedef __bf16 bf16x8 __attribute__((ext_vector_type(8)));
typedef __bf16 bf16x4 __attribute__((ext_vector_type(4)));
typedef float f32x4 __attribute__((ext_vector_type(4)));
typedef float f32x16 __attribute__((ext_vector_type(16)));
typedef unsigned int uint4v __attribute__((ext_vector_type(4)));
typedef unsigned short ushort4v __attribute__((ext_vector_type(4)));
using u16 = unsigned short;

#define NN 2048
#define DIMD 1024

DEV u16 f2bf(float f) {  // RNE via hardware cvt
    __bf16 b = (__bf16)f;
    return __builtin_bit_cast(u16, b);
}
DEV float bf2f(u16 s) {
    unsigned u = ((unsigned)s) << 16;
    return __builtin_bit_cast(float, u);
}
DEV bf16x8 load16(const u16* p) { return __builtin_bit_cast(bf16x8, *(const uint4v*)p); }
DEV f32x4 mfma16(bf16x8 a, bf16x8 b, f32x4 c) {
    return __builtin_amdgcn_mfma_f32_16x16x32_bf16(a, b, c, 0, 0, 0);
}
DEV f32x16 mfma32(bf16x8 a, bf16x8 b, f32x16 c) {
    return __builtin_amdgcn_mfma_f32_32x32x16_bf16(a, b, c, 0, 0, 0);
}
// async global->LDS, 16B per lane; lds base must be wave-uniform
DEV void gl_lds16(const u16* g, u16* l) {
    __builtin_amdgcn_global_load_lds((const __attribute__((address_space(1))) void*)g,
                                     (__attribute__((address_space(3))) void*)l, 16, 0, 0);
}

// ---------------- prep kernels ----------------

__global__ __launch_bounds__(256) void k_pack_x(const float* __restrict__ x,
                                                u16* __restrict__ xb, int n4) {
    int i = blockIdx.x * 256 + threadIdx.x;
    if (i >= n4) return;
    float4 v = ((const float4*)x)[i];
    ushort4v o;
    o[0] = f2bf(v.x); o[1] = f2bf(v.y); o[2] = f2bf(v.z); o[3] = f2bf(v.w);
    *(ushort4v*)(xb + (size_t)i * 4) = o;
}

// dst[n][k] = src[k][n], 1024x1024, fp32 -> bf16
__global__ __launch_bounds__(256) void k_transpose_w(const float* __restrict__ s0,
                                                     const float* __restrict__ s1,
                                                     const float* __restrict__ s2,
                                                     const float* __restrict__ s3,
                                                     u16* __restrict__ wqkv_t,
                                                     u16* __restrict__ wo_t) {
    __shared__ float tile[32][33];
    int z = blockIdx.z;
    const float* src = (z == 0) ? s0 : (z == 1) ? s1 : (z == 2) ? s2 : s3;
    u16* dst = (z < 3) ? (wqkv_t + (size_t)z * 1024 * 1024) : wo_t;
    int tx = threadIdx.x & 31, ty = threadIdx.x >> 5;  // ty 0..7
    int kb = blockIdx.y * 32, nb = blockIdx.x * 32;
#pragma unroll
    for (int j = 0; j < 4; ++j)
        tile[ty + 8 * j][tx] = src[(size_t)(kb + ty + 8 * j) * 1024 + nb + tx];
    __syncthreads();
#pragma unroll
    for (int j = 0; j < 4; ++j)
        dst[(size_t)(nb + ty + 8 * j) * 1024 + kb + tx] = f2bf(tile[tx][ty + 8 * j]);
}

// ---------------- QKV GEMM with fused bias + LayerNorm + fragment-linear write ----------------
// C[m][n] = xb[m][K] * wqkv_t[n][K]^T, K=1024, tile 128x128 (m97 staging).
// Epilogue: cols<2048 -> per-head LN (over d=64) -> Qf/Kf fragment-linear;
//           cols>=2048 -> bias -> Vf fragment-linear.
// Fragment-linear layouts (per bh, 131072 u16):
//   Qf/Kf: ((n>>5)*4 + (d>>4))*512 + (((d>>3)&1)*32 + (n&31))*8 + (d&7)
//   Vf:    ((j>>5)*4 + (d>>5)*2 + ((j>>4)&1))*512 + (((j>>3)&1)*32 + (d&31))*8 + (j&7)
__global__ __launch_bounds__(256) void k_gemm_qkv(const u16* __restrict__ A,
                                                  const u16* __restrict__ Bt,
                                                  const float* __restrict__ bq,
                                                  const float* __restrict__ bk,
                                                  const float* __restrict__ bv,
                                                  const float* __restrict__ qs,
                                                  const float* __restrict__ qb,
                                                  const float* __restrict__ ks,
                                                  const float* __restrict__ kb_,
                                                  u16* __restrict__ Qf,
                                                  u16* __restrict__ Kf,
                                                  u16* __restrict__ Vf) {
    __shared__ u16 As[128 * 32];
    __shared__ u16 Bs[128 * 32];
    const int K = 1024;
    const int m0 = blockIdx.x * 128, n0 = blockIdx.y * 128;
    const int tid = threadIdx.x;
    const int lane = tid & 63, w = tid >> 6;
    const int wr = w >> 1, wc = w & 1;
    const int li = lane & 15, g = lane >> 4;

    f32x4 acc[4][4] = {};

    const u16* gA = A + (size_t)(m0 + w * 16 + (lane >> 2)) * K + (lane & 3) * 8;
    const u16* gB = Bt + (size_t)(n0 + w * 16 + (lane >> 2)) * K + (lane & 3) * 8;
    u16* lA = &As[(w * 16) * 32];
    u16* lB = &Bs[(w * 16) * 32];

    for (int k0 = 0; k0 < K; k0 += 32) {
        __syncthreads();
        gl_lds16(gA + k0, lA);
        gl_lds16(gA + (size_t)64 * K + k0, lA + 64 * 32);
        gl_lds16(gB + k0, lB);
        gl_lds16(gB + (size_t)64 * K + k0, lB + 64 * 32);
        asm volatile("s_waitcnt vmcnt(0)" ::: "memory");
        __syncthreads();
        bf16x8 af[4], bfv[4];
#pragma unroll
        for (int mi = 0; mi < 4; ++mi)
            af[mi] = load16(&As[(wr * 64 + mi * 16 + li) * 32 + g * 8]);
#pragma unroll
        for (int ni = 0; ni < 4; ++ni)
            bfv[ni] = load16(&Bs[(wc * 64 + ni * 16 + li) * 32 + g * 8]);
#pragma unroll
        for (int mi = 0; mi < 4; ++mi)
#pragma unroll
            for (int ni = 0; ni < 4; ++ni)
                acc[mi][ni] = mfma16(af[mi], bfv[ni], acc[mi][ni]);
    }

    // ---- fused epilogue ----
    const int col0 = n0 + wc * 64;        // 64-aligned head segment base
    const int seg = col0 >> 10;           // 0=q, 1=k, 2=v
    const int hcol = col0 & 1023;         // col base within its matrix
    const int h = hcol >> 6;

    if (seg < 2) {
        const float* S = (seg == 0) ? qs : ks;
        const float* Bb = (seg == 0) ? qb : kb_;
        const float* bias = (seg == 0) ? bq : bk;
        u16* dst = (seg == 0) ? Qf : Kf;
        float lnS[4], lnB[4], bv4[4];
#pragma unroll
        for (int ni = 0; ni < 4; ++ni) {
            int d = ni * 16 + li;
            lnS[ni] = S[d]; lnB[ni] = Bb[d]; bv4[ni] = bias[hcol + d];
        }
#pragma unroll
        for (int mi = 0; mi < 4; ++mi) {
#pragma unroll
            for (int r = 0; r < 4; ++r) {
                float v0 = acc[mi][0][r] + bv4[0];
                float v1 = acc[mi][1][r] + bv4[1];
                float v2 = acc[mi][2][r] + bv4[2];
                float v3 = acc[mi][3][r] + bv4[3];
                float s1 = v0 + v1 + v2 + v3;
                float s2 = v0 * v0 + v1 * v1 + v2 * v2 + v3 * v3;
#pragma unroll
                for (int o = 1; o < 16; o <<= 1) {
                    s1 += __shfl_xor(s1, o);
                    s2 += __shfl_xor(s2, o);
                }
                float mu = s1 * (1.0f / 64.0f);
                float var = s2 * (1.0f / 64.0f) - mu * mu;
                float rsv = rsqrtf(var + 1e-6f);
                int row = m0 + wr * 64 + mi * 16 + 4 * g + r;
                int bseq = row >> 11, n = row & 2047;
                size_t base = ((size_t)(bseq * 16 + h)) * 131072 +
                              ((size_t)(n >> 5) * 4) * 512 + (size_t)(n & 31) * 8 +
                              (li >> 3) * 256 + (li & 7);
                dst[base + 0 * 512] = f2bf((v0 - mu) * rsv * lnS[0] + lnB[0]);
                dst[base + 1 * 512] = f2bf((v1 - mu) * rsv * lnS[1] + lnB[1]);
                dst[base + 2 * 512] = f2bf((v2 - mu) * rsv * lnS[2] + lnB[2]);
                dst[base + 3 * 512] = f2bf((v3 - mu) * rsv * lnS[3] + lnB[3]);
            }
        }
    } else {
        float bv4[4];
#pragma unroll
        for (int ni = 0; ni < 4; ++ni) bv4[ni] = bv[hcol + ni * 16 + li];
#pragma unroll
        for (int mi = 0; mi < 4; ++mi) {
#pragma unroll
            for (int r = 0; r < 4; ++r) {
                int row = m0 + wr * 64 + mi * 16 + 4 * g + r;
                int bseq = row >> 11, j = row & 2047;
                size_t vb_ = ((size_t)(bseq * 16 + h)) * 131072 +
                             ((size_t)((j >> 5) * 4 + ((j >> 4) & 1))) * 512 +
                             (size_t)(((j >> 3) & 1) * 32) * 8 + (j & 7);
#pragma unroll
                for (int ni = 0; ni < 4; ++ni)
                    Vf[vb_ + (ni >> 1) * 1024 + ((ni & 1) * 16 + li) * 8] =
                        f2bf(acc[mi][ni][r] + bv4[ni]);
            }
        }
    }
}

// ---------------- output GEMM: out fp32 = (acc + bo[n]) * gamma[n] ----------------
__global__ __launch_bounds__(256) void k_gemm_out(const u16* __restrict__ A,
                                                  const u16* __restrict__ Bt,
                                                  const float* __restrict__ bias,
                                                  const float* __restrict__ gamma,
                                                  float* __restrict__ out) {
    __shared__ u16 As[128 * 32];
    __shared__ u16 Bs[128 * 32];
    const int K = 1024, ldc = 1024;
    const int m0 = blockIdx.x * 128, n0 = blockIdx.y * 128;
    const int tid = threadIdx.x;
    const int lane = tid & 63, w = tid >> 6;
    const int wr = w >> 1, wc = w & 1;
    const int li = lane & 15, g = lane >> 4;

    f32x4 acc[4][4] = {};

    const u16* gA = A + (size_t)(m0 + w * 16 + (lane >> 2)) * K + (lane & 3) * 8;
    const u16* gB = Bt + (size_t)(n0 + w * 16 + (lane >> 2)) * K + (lane & 3) * 8;
    u16* lA = &As[(w * 16) * 32];
    u16* lB = &Bs[(w * 16) * 32];

    for (int k0 = 0; k0 < K; k0 += 32) {
        __syncthreads();
        gl_lds16(gA + k0, lA);
        gl_lds16(gA + (size_t)64 * K + k0, lA + 64 * 32);
        gl_lds16(gB + k0, lB);
        gl_lds16(gB + (size_t)64 * K + k0, lB + 64 * 32);
        asm volatile("s_waitcnt vmcnt(0)" ::: "memory");
        __syncthreads();
        bf16x8 af[4], bfv[4];
#pragma unroll
        for (int mi = 0; mi < 4; ++mi)
            af[mi] = load16(&As[(wr * 64 + mi * 16 + li) * 32 + g * 8]);
#pragma unroll
        for (int ni = 0; ni < 4; ++ni)
            bfv[ni] = load16(&Bs[(wc * 64 + ni * 16 + li) * 32 + g * 8]);
#pragma unroll
        for (int mi = 0; mi < 4; ++mi)
#pragma unroll
            for (int ni = 0; ni < 4; ++ni)
                acc[mi][ni] = mfma16(af[mi], bfv[ni], acc[mi][ni]);
    }

#pragma unroll
    for (int mi = 0; mi < 4; ++mi) {
        int row = m0 + wr * 64 + mi * 16 + 4 * g;
#pragma unroll
        for (int ni = 0; ni < 4; ++ni) {
            int col = n0 + wc * 64 + ni * 16 + li;
            float bv_ = bias[col], gv = gamma[col];
            f32x4 v = acc[mi][ni];
#pragma unroll
            for (int r = 0; r < 4; ++r)
                out[(size_t)(row + r) * ldc + col] = (v[r] + bv_) * gv;
        }
    }
}

// ---------------- fused sigmoid attention v6 (software-pipelined) ----------------
// Fragment-linear inputs; block = 64 queries x 4 waves (j-quarters).
// Per jt: prefetch K[jt+1]; load V[jt]; QK(K[jt]); sigmoid via
// rcp(1+exp2(fma)); pack (cvt_pk + permlane32_swap); PV. K prefetch and V
// latency hide under the ~700-cyc sigmoid VALU block; MFMA executes under
// the next iteration's VALU. Cross-wave combine at end via pad-65 LDS.
__global__ __launch_bounds__(256) void k_attn(const u16* __restrict__ Qf,
                                              const u16* __restrict__ Kf,
                                              const u16* __restrict__ Vf,
                                              const float* __restrict__ ib,
                                              u16* __restrict__ attn_out) {
    __shared__ float red[2][64][65];
    const int bid = blockIdx.x;
    const int xcd = bid & 7, idx = bid >> 3;  // 1024 blocks: 128 per XCD
    const int bh = xcd * 4 + (idx >> 5);      // 4 bh per XCD -> K/V L2-resident
    const int iblk = idx & 31;
    const int b = bh >> 4, h = bh & 15;
    const int tid = threadIdx.x;
    const int jq = tid >> 6, lane = tid & 63;
    const int l32 = lane & 31, hi = lane >> 5;
    const float c0 = -ib[0] * 1.44269504f;  // exp2(c1*sa + c0) = exp(-(sa+bias))
    const float c1 = -1.44269504f;
    const u16* Qb = Qf + (size_t)bh * 131072;
    const u16* Kb = Kf + (size_t)bh * 131072;
    const u16* Vb = Vf + (size_t)bh * 131072;
    const int it0 = iblk * 2;

    bf16x8 qf[2][4];
#pragma unroll
    for (int t = 0; t < 2; ++t)
#pragma unroll
        for (int s = 0; s < 4; ++s)
            qf[t][s] = load16(Qb + ((size_t)((it0 + t) * 4 + s)) * 512 + lane * 8);

    f32x16 accO[2][2] = {};
    const u16* kb0 = Kb + (size_t)(jq * 16) * 2048;
    const u16* vb0 = Vb + (size_t)(jq * 16) * 2048;

    // prologue: K fragments for jt=0
    bf16x8 kf[2][4];
#pragma unroll
    for (int s = 0; s < 4; ++s) kf[0][s] = load16(kb0 + s * 512 + lane * 8);

#pragma unroll
    for (int jt = 0; jt < 16; ++jt) {
        const int cur = jt & 1, nxt = cur ^ 1;
        // prefetch next K fragments (consumed next iteration)
        if (jt < 15) {
            const u16* kbn = kb0 + (size_t)(jt + 1) * 2048;
#pragma unroll
            for (int s = 0; s < 4; ++s) kf[nxt][s] = load16(kbn + s * 512 + lane * 8);
        }
        // V fragments for this jt (consumed ~700 cyc later by PV)
        bf16x8 vf[2][2];
        const u16* vbc = vb0 + (size_t)jt * 2048;
#pragma unroll
        for (int db = 0; db < 2; ++db)
#pragma unroll
            for (int js = 0; js < 2; ++js)
                vf[db][js] = load16(vbc + (db * 2 + js) * 512 + lane * 8);
        // QK^T: both i-tiles, independent chains
        __builtin_amdgcn_s_setprio(1);
        f32x16 sa[2] = {f32x16{}, f32x16{}};
#pragma unroll
        for (int s = 0; s < 4; ++s) sa[0] = mfma32(kf[cur][s], qf[0][s], sa[0]);
#pragma unroll
        for (int s = 0; s < 4; ++s) sa[1] = mfma32(kf[cur][s], qf[1][s], sa[1]);
        __builtin_amdgcn_s_setprio(0);
        // sigmoid + pack per i-tile (T12)
        bf16x8 pb[2][2];
#pragma unroll
        for (int t = 0; t < 2; ++t) {
            float p[16];
#pragma unroll
            for (int r = 0; r < 16; ++r) {
                float e = __builtin_amdgcn_exp2f(fmaf(sa[t][r], c1, c0));
                p[r] = __builtin_amdgcn_rcpf(1.0f + e);
            }
            unsigned wd[8];
#pragma unroll
            for (int u = 0; u < 8; ++u) {
                unsigned r_;
                asm("v_cvt_pk_bf16_f32 %0, %1, %2"
                    : "=v"(r_) : "v"(p[2 * u]), "v"(p[2 * u + 1]));
                wd[u] = r_;
            }
            asm("v_permlane32_swap_b32 %0, %1" : "+v"(wd[0]), "+v"(wd[2]));
            asm("v_permlane32_swap_b32 %0, %1" : "+v"(wd[1]), "+v"(wd[3]));
            asm("v_permlane32_swap_b32 %0, %1" : "+v"(wd[4]), "+v"(wd[6]));
            asm("v_permlane32_swap_b32 %0, %1" : "+v"(wd[5]), "+v"(wd[7]));
            uint4v u0 = {wd[0], wd[1], wd[2], wd[3]};
            uint4v u1 = {wd[4], wd[5], wd[6], wd[7]};
            pb[t][0] = __builtin_bit_cast(bf16x8, u0);
            pb[t][1] = __builtin_bit_cast(bf16x8, u1);
        }
        // PV
        __builtin_amdgcn_s_setprio(1);
#pragma unroll
        for (int t = 0; t < 2; ++t)
#pragma unroll
            for (int db = 0; db < 2; ++db)
#pragma unroll
                for (int js = 0; js < 2; ++js)
                    accO[t][db] = mfma32(vf[db][js], pb[t][js], accO[t][db]);
        __builtin_amdgcn_s_setprio(0);
    }

    // cross-wave combine (d = db*32 + (r&3)+8(r>>2)+4hi)
    if (jq & 1) {
#pragma unroll
        for (int t = 0; t < 2; ++t)
#pragma unroll
            for (int db = 0; db < 2; ++db)
#pragma unroll
                for (int r = 0; r < 16; ++r)
                    red[jq >> 1][t * 32 + l32][db * 32 + (r & 3) + 8 * (r >> 2) + 4 * hi] =
                        accO[t][db][r];
    }
    __syncthreads();
    if (!(jq & 1)) {
#pragma unroll
        for (int t = 0; t < 2; ++t)
#pragma unroll
            for (int db = 0; db < 2; ++db)
#pragma unroll
                for (int r = 0; r < 16; ++r)
                    accO[t][db][r] +=
                        red[jq >> 1][t * 32 + l32][db * 32 + (r & 3) + 8 * (r >> 2) + 4 * hi];
    }
    __syncthreads();
    if (jq == 2) {
#pragma unroll
        for (int t = 0; t < 2; ++t)
#pragma unroll
            for (int db = 0; db < 2; ++db)
#pragma unroll
                for (int r = 0; r < 16; ++r)
                    red[0][t * 32 + l32][db * 32 + (r & 3) + 8 * (r >> 2) + 4 * hi] =
                        accO[t][db][r];
    }
    __syncthreads();
    if (jq == 0) {
#pragma unroll
        for (int t = 0; t < 2; ++t)
#pragma unroll
            for (int db = 0; db < 2; ++db)
#pragma unroll
                for (int r = 0; r < 16; ++r)
                    accO[t][db][r] +=
                        red[0][t * 32 + l32][db * 32 + (r & 3) + 8 * (r >> 2) + 4 * hi];
#pragma unroll
        for (int t = 0; t < 2; ++t) {
            const int i = it0 * 32 + t * 32 + l32;
#pragma unroll
            for (int db = 0; db < 2; ++db)
#pragma unroll
                for (int q = 0; q < 4; ++q) {
                    int d = db * 32 + 8 * q + 4 * hi;
                    bf16x4 o4;
#pragma unroll
                    for (int r = 0; r < 4; ++r) o4[r] = (__bf16)accO[t][db][4 * q + r];
                    *(bf16x4*)&attn_out[(size_t)(b * NN + i) * 1024 + h * 64 + d] = o4;
                }
        }
    }
}

// ---------------- launch ----------------

extern "C" void kernel_launch(void* const* d_in, const int* in_sizes, int n_in,
                              void* d_out, int out_size, void* d_ws, size_t ws_size,
                              hipStream_t stream) {
    (void)in_sizes; (void)n_in; (void)out_size; (void)ws_size;
    const float* x     = (const float*)d_in[0];
    const float* Wq    = (const float*)d_in[1];
    const float* bq    = (const float*)d_in[2];
    const float* Wk    = (const float*)d_in[3];
    const float* bk    = (const float*)d_in[4];
    const float* Wv    = (const float*)d_in[5];
    const float* bv    = (const float*)d_in[6];
    const float* qn_s  = (const float*)d_in[7];
    const float* qn_b  = (const float*)d_in[8];
    const float* kn_s  = (const float*)d_in[9];
    const float* kn_b  = (const float*)d_in[10];
    const float* ib    = (const float*)d_in[11];
    const float* Wo    = (const float*)d_in[12];
    const float* bo    = (const float*)d_in[13];
    const float* gamma = (const float*)d_in[14];
    float* out = (float*)d_out;

    char* ws = (char*)d_ws;
    size_t off = 0;
    auto alloc = [&](size_t bytes) -> void* {
        void* p = ws + off;
        off += (bytes + 255) & ~(size_t)255;
        return p;
    };
    u16* xb       = (u16*)alloc((size_t)4096 * 1024 * 2);   // x bf16
    u16* wqkv_t   = (u16*)alloc((size_t)3072 * 1024 * 2);   // [n][k]
    u16* wo_t     = (u16*)alloc((size_t)1024 * 1024 * 2);
    u16* Qf       = (u16*)alloc((size_t)32 * 131072 * 2);   // fragment-linear
    u16* Kf       = (u16*)alloc((size_t)32 * 131072 * 2);
    u16* Vf       = (u16*)alloc((size_t)32 * 131072 * 2);
    u16* attn_out = (u16*)alloc((size_t)4096 * 1024 * 2);

    k_pack_x<<<4096, 256, 0, stream>>>(x, xb, 1048576);
    k_transpose_w<<<dim3(32, 32, 4), 256, 0, stream>>>(Wq, Wk, Wv, Wo, wqkv_t, wo_t);
    k_gemm_qkv<<<dim3(32, 24), 256, 0, stream>>>(xb, wqkv_t, bq, bk, bv,
                                                 qn_s, qn_b, kn_s, kn_b, Qf, Kf, Vf);
    k_attn<<<1024, 256, 0, stream>>>(Qf, Kf, Vf, ib, attn_out);
    k_gemm_out<<<dim3(32, 8), 256, 0, stream>>>(attn_out, wo_t, bo, gamma, out);
}

// Round 7
// 126.464 us; speedup vs baseline: 1.6952x; 1.0389x over previous
//
#include <hip/hip_runtime.h>

#define DEV static __device__ __forceinline__

typedef __bf16 bf16x8 __attribute__((ext_vector_type(8)));
typedef __bf16 bf16x4 __attribute__((ext_vector_type(4)));
typedef float f32x4 __attribute__((ext_vector_type(4)));
typedef float f32x16 __attribute__((ext_vector_type(16)));
typedef unsigned int uint4v __attribute__((ext_vector_type(4)));
typedef unsigned short ushort4v __attribute__((ext_vector_type(4)));
using u16 = unsigned short;

#define NN 2048
#define DIMD 1024

DEV u16 f2bf(float f) {  // RNE via hardware cvt
    __bf16 b = (__bf16)f;
    return __builtin_bit_cast(u16, b);
}
DEV float bf2f(u16 s) {
    unsigned u = ((unsigned)s) << 16;
    return __builtin_bit_cast(float, u);
}
DEV bf16x8 load16(const u16* p) { return __builtin_bit_cast(bf16x8, *(const uint4v*)p); }
DEV f32x4 mfma16(bf16x8 a, bf16x8 b, f32x4 c) {
    return __builtin_amdgcn_mfma_f32_16x16x32_bf16(a, b, c, 0, 0, 0);
}
DEV f32x16 mfma32(bf16x8 a, bf16x8 b, f32x16 c) {
    return __builtin_amdgcn_mfma_f32_32x32x16_bf16(a, b, c, 0, 0, 0);
}
// async global->LDS, 16B per lane; lds base must be wave-uniform
DEV void gl_lds16(const u16* g, u16* l) {
    __builtin_amdgcn_global_load_lds((const __attribute__((address_space(1))) void*)g,
                                     (__attribute__((address_space(3))) void*)l, 16, 0, 0);
}

// ---------------- prep: W transposes (z<4) + x bf16 pack (z==4) ----------------

__global__ __launch_bounds__(256) void k_prep(const float* __restrict__ x,
                                              const float* __restrict__ s0,
                                              const float* __restrict__ s1,
                                              const float* __restrict__ s2,
                                              const float* __restrict__ s3,
                                              u16* __restrict__ xb,
                                              u16* __restrict__ wqkv_t,
                                              u16* __restrict__ wo_t) {
    __shared__ float tile[32][33];
    const int z = blockIdx.z;
    if (z < 4) {
        const float* src = (z == 0) ? s0 : (z == 1) ? s1 : (z == 2) ? s2 : s3;
        u16* dst = (z < 3) ? (wqkv_t + (size_t)z * 1024 * 1024) : wo_t;
        int tx = threadIdx.x & 31, ty = threadIdx.x >> 5;  // ty 0..7
        int kb = blockIdx.y * 32, nb = blockIdx.x * 32;
#pragma unroll
        for (int j = 0; j < 4; ++j)
            tile[ty + 8 * j][tx] = src[(size_t)(kb + ty + 8 * j) * 1024 + nb + tx];
        __syncthreads();
#pragma unroll
        for (int j = 0; j < 4; ++j)
            dst[(size_t)(nb + ty + 8 * j) * 1024 + kb + tx] = f2bf(tile[tx][ty + 8 * j]);
    } else {
        // pack x: 1,048,576 float4 -> bf16x4; 1024 blocks x 256 thr x 4 each
        const int bidx = blockIdx.y * 32 + blockIdx.x;
#pragma unroll
        for (int q = 0; q < 4; ++q) {
            int i = bidx * 1024 + q * 256 + threadIdx.x;
            float4 v = ((const float4*)x)[i];
            ushort4v o;
            o[0] = f2bf(v.x); o[1] = f2bf(v.y); o[2] = f2bf(v.z); o[3] = f2bf(v.w);
            *(ushort4v*)(xb + (size_t)i * 4) = o;
        }
    }
}

// ---------------- QKV GEMM with fused bias + LayerNorm + fragment-linear write ----------------
// C[m][n] = xb[m][K] * wqkv_t[n][K]^T, K=1024, tile 128x128 (m97 staging).
// Epilogue: cols<2048 -> per-head LN (over d=64) -> Qf/Kf fragment-linear;
//           cols>=2048 -> bias -> Vf fragment-linear.
// Fragment-linear layouts (per bh, 131072 u16):
//   Qf/Kf: ((n>>5)*4 + (d>>4))*512 + (((d>>3)&1)*32 + (n&31))*8 + (d&7)
//   Vf:    ((j>>5)*4 + (d>>5)*2 + ((j>>4)&1))*512 + (((j>>3)&1)*32 + (d&31))*8 + (j&7)
__global__ __launch_bounds__(256) void k_gemm_qkv(const u16* __restrict__ A,
                                                  const u16* __restrict__ Bt,
                                                  const float* __restrict__ bq,
                                                  const float* __restrict__ bk,
                                                  const float* __restrict__ bv,
                                                  const float* __restrict__ qs,
                                                  const float* __restrict__ qb,
                                                  const float* __restrict__ ks,
                                                  const float* __restrict__ kb_,
                                                  u16* __restrict__ Qf,
                                                  u16* __restrict__ Kf,
                                                  u16* __restrict__ Vf) {
    __shared__ u16 As[128 * 32];
    __shared__ u16 Bs[128 * 32];
    const int K = 1024;
    const int m0 = blockIdx.x * 128, n0 = blockIdx.y * 128;
    const int tid = threadIdx.x;
    const int lane = tid & 63, w = tid >> 6;
    const int wr = w >> 1, wc = w & 1;
    const int li = lane & 15, g = lane >> 4;

    f32x4 acc[4][4] = {};

    const u16* gA = A + (size_t)(m0 + w * 16 + (lane >> 2)) * K + (lane & 3) * 8;
    const u16* gB = Bt + (size_t)(n0 + w * 16 + (lane >> 2)) * K + (lane & 3) * 8;
    u16* lA = &As[(w * 16) * 32];
    u16* lB = &Bs[(w * 16) * 32];

    for (int k0 = 0; k0 < K; k0 += 32) {
        __syncthreads();
        gl_lds16(gA + k0, lA);
        gl_lds16(gA + (size_t)64 * K + k0, lA + 64 * 32);
        gl_lds16(gB + k0, lB);
        gl_lds16(gB + (size_t)64 * K + k0, lB + 64 * 32);
        asm volatile("s_waitcnt vmcnt(0)" ::: "memory");
        __syncthreads();
        bf16x8 af[4], bfv[4];
#pragma unroll
        for (int mi = 0; mi < 4; ++mi)
            af[mi] = load16(&As[(wr * 64 + mi * 16 + li) * 32 + g * 8]);
#pragma unroll
        for (int ni = 0; ni < 4; ++ni)
            bfv[ni] = load16(&Bs[(wc * 64 + ni * 16 + li) * 32 + g * 8]);
#pragma unroll
        for (int mi = 0; mi < 4; ++mi)
#pragma unroll
            for (int ni = 0; ni < 4; ++ni)
                acc[mi][ni] = mfma16(af[mi], bfv[ni], acc[mi][ni]);
    }

    // ---- fused epilogue ----
    const int col0 = n0 + wc * 64;        // 64-aligned head segment base
    const int seg = col0 >> 10;           // 0=q, 1=k, 2=v
    const int hcol = col0 & 1023;         // col base within its matrix
    const int h = hcol >> 6;

    if (seg < 2) {
        const float* S = (seg == 0) ? qs : ks;
        const float* Bb = (seg == 0) ? qb : kb_;
        const float* bias = (seg == 0) ? bq : bk;
        u16* dst = (seg == 0) ? Qf : Kf;
        float lnS[4], lnB[4], bv4[4];
#pragma unroll
        for (int ni = 0; ni < 4; ++ni) {
            int d = ni * 16 + li;
            lnS[ni] = S[d]; lnB[ni] = Bb[d]; bv4[ni] = bias[hcol + d];
        }
#pragma unroll
        for (int mi = 0; mi < 4; ++mi) {
#pragma unroll
            for (int r = 0; r < 4; ++r) {
                float v0 = acc[mi][0][r] + bv4[0];
                float v1 = acc[mi][1][r] + bv4[1];
                float v2 = acc[mi][2][r] + bv4[2];
                float v3 = acc[mi][3][r] + bv4[3];
                float s1 = v0 + v1 + v2 + v3;
                float s2 = v0 * v0 + v1 * v1 + v2 * v2 + v3 * v3;
#pragma unroll
                for (int o = 1; o < 16; o <<= 1) {
                    s1 += __shfl_xor(s1, o);
                    s2 += __shfl_xor(s2, o);
                }
                float mu = s1 * (1.0f / 64.0f);
                float var = s2 * (1.0f / 64.0f) - mu * mu;
                float rsv = rsqrtf(var + 1e-6f);
                int row = m0 + wr * 64 + mi * 16 + 4 * g + r;
                int bseq = row >> 11, n = row & 2047;
                size_t base = ((size_t)(bseq * 16 + h)) * 131072 +
                              ((size_t)(n >> 5) * 4) * 512 + (size_t)(n & 31) * 8 +
                              (li >> 3) * 256 + (li & 7);
                dst[base + 0 * 512] = f2bf((v0 - mu) * rsv * lnS[0] + lnB[0]);
                dst[base + 1 * 512] = f2bf((v1 - mu) * rsv * lnS[1] + lnB[1]);
                dst[base + 2 * 512] = f2bf((v2 - mu) * rsv * lnS[2] + lnB[2]);
                dst[base + 3 * 512] = f2bf((v3 - mu) * rsv * lnS[3] + lnB[3]);
            }
        }
    } else {
        float bv4[4];
#pragma unroll
        for (int ni = 0; ni < 4; ++ni) bv4[ni] = bv[hcol + ni * 16 + li];
#pragma unroll
        for (int mi = 0; mi < 4; ++mi) {
#pragma unroll
            for (int r = 0; r < 4; ++r) {
                int row = m0 + wr * 64 + mi * 16 + 4 * g + r;
                int bseq = row >> 11, j = row & 2047;
                size_t vb_ = ((size_t)(bseq * 16 + h)) * 131072 +
                             ((size_t)((j >> 5) * 4 + ((j >> 4) & 1))) * 512 +
                             (size_t)(((j >> 3) & 1) * 32) * 8 + (j & 7);
#pragma unroll
                for (int ni = 0; ni < 4; ++ni)
                    Vf[vb_ + (ni >> 1) * 1024 + ((ni & 1) * 16 + li) * 8] =
                        f2bf(acc[mi][ni][r] + bv4[ni]);
            }
        }
    }
}

// ---------------- output GEMM: out fp32 = (acc + bo[n]) * gamma[n] ----------------
__global__ __launch_bounds__(256) void k_gemm_out(const u16* __restrict__ A,
                                                  const u16* __restrict__ Bt,
                                                  const float* __restrict__ bias,
                                                  const float* __restrict__ gamma,
                                                  float* __restrict__ out) {
    __shared__ u16 As[128 * 32];
    __shared__ u16 Bs[128 * 32];
    const int K = 1024, ldc = 1024;
    const int m0 = blockIdx.x * 128, n0 = blockIdx.y * 128;
    const int tid = threadIdx.x;
    const int lane = tid & 63, w = tid >> 6;
    const int wr = w >> 1, wc = w & 1;
    const int li = lane & 15, g = lane >> 4;

    f32x4 acc[4][4] = {};

    const u16* gA = A + (size_t)(m0 + w * 16 + (lane >> 2)) * K + (lane & 3) * 8;
    const u16* gB = Bt + (size_t)(n0 + w * 16 + (lane >> 2)) * K + (lane & 3) * 8;
    u16* lA = &As[(w * 16) * 32];
    u16* lB = &Bs[(w * 16) * 32];

    for (int k0 = 0; k0 < K; k0 += 32) {
        __syncthreads();
        gl_lds16(gA + k0, lA);
        gl_lds16(gA + (size_t)64 * K + k0, lA + 64 * 32);
        gl_lds16(gB + k0, lB);
        gl_lds16(gB + (size_t)64 * K + k0, lB + 64 * 32);
        asm volatile("s_waitcnt vmcnt(0)" ::: "memory");
        __syncthreads();
        bf16x8 af[4], bfv[4];
#pragma unroll
        for (int mi = 0; mi < 4; ++mi)
            af[mi] = load16(&As[(wr * 64 + mi * 16 + li) * 32 + g * 8]);
#pragma unroll
        for (int ni = 0; ni < 4; ++ni)
            bfv[ni] = load16(&Bs[(wc * 64 + ni * 16 + li) * 32 + g * 8]);
#pragma unroll
        for (int mi = 0; mi < 4; ++mi)
#pragma unroll
            for (int ni = 0; ni < 4; ++ni)
                acc[mi][ni] = mfma16(af[mi], bfv[ni], acc[mi][ni]);
    }

#pragma unroll
    for (int mi = 0; mi < 4; ++mi) {
        int row = m0 + wr * 64 + mi * 16 + 4 * g;
#pragma unroll
        for (int ni = 0; ni < 4; ++ni) {
            int col = n0 + wc * 64 + ni * 16 + li;
            float bv_ = bias[col], gv = gamma[col];
            f32x4 v = acc[mi][ni];
#pragma unroll
            for (int r = 0; r < 4; ++r)
                out[(size_t)(row + r) * ldc + col] = (v[r] + bv_) * gv;
        }
    }
}

// ---------------- fused sigmoid attention v7: i-tile ping-pong pipeline ----------------
// Wave owns two 32-query i-tiles + a 512-key j-quarter. Per jt the stages are
// ordered so every sa read is >= 8 MFMAs + one sigmoid block away from its
// producing QK chain (T15): QK[t1][jt] || sigmoid[t0] ; QK[t0][jt+1] || sigmoid[t1].
// sched_barrier(0) pins stage order. Cross-wave combine via pad-65 LDS at end.
__global__ __launch_bounds__(256, 2) void k_attn(const u16* __restrict__ Qf,
                                                 const u16* __restrict__ Kf,
                                                 const u16* __restrict__ Vf,
                                                 const float* __restrict__ ib,
                                                 u16* __restrict__ attn_out) {
    __shared__ float red[2][64][65];
    const int bid = blockIdx.x;
    const int xcd = bid & 7, idx = bid >> 3;  // 1024 blocks: 128 per XCD
    const int bh = xcd * 4 + (idx >> 5);      // 4 bh per XCD -> K/V L2-resident
    const int iblk = idx & 31;
    const int b = bh >> 4, h = bh & 15;
    const int tid = threadIdx.x;
    const int jq = tid >> 6, lane = tid & 63;
    const int l32 = lane & 31, hi = lane >> 5;
    const float c0 = -ib[0] * 1.44269504f;  // exp2(c1*sa + c0) = exp(-(sa+bias))
    const float c1 = -1.44269504f;
    const u16* Qb = Qf + (size_t)bh * 131072;
    const u16* Kb = Kf + (size_t)bh * 131072;
    const u16* Vb = Vf + (size_t)bh * 131072;
    const int it0 = iblk * 2;

    bf16x8 qf[2][4];
#pragma unroll
    for (int t = 0; t < 2; ++t)
#pragma unroll
        for (int s = 0; s < 4; ++s)
            qf[t][s] = load16(Qb + ((size_t)((it0 + t) * 4 + s)) * 512 + lane * 8);

    f32x16 accO[2][2] = {};
    const u16* kb0 = Kb + (size_t)(jq * 16) * 2048;
    const u16* vb0 = Vb + (size_t)(jq * 16) * 2048;

    // prologue: K tiles 0,1; QK[t0][0]
    bf16x8 kf[2][4];
#pragma unroll
    for (int s = 0; s < 4; ++s) kf[0][s] = load16(kb0 + s * 512 + lane * 8);
#pragma unroll
    for (int s = 0; s < 4; ++s) kf[1][s] = load16(kb0 + 2048 + s * 512 + lane * 8);
    f32x16 sa0 = {}, sa1;
#pragma unroll
    for (int s = 0; s < 4; ++s) sa0 = mfma32(kf[0][s], qf[0][s], sa0);

#pragma unroll
    for (int jt = 0; jt < 16; ++jt) {
        const int cur = jt & 1, nxt = cur ^ 1;
        // V fragments for this jt (consumed by PV below; latency under QK issue)
        bf16x8 vf[2][2];
        const u16* vbc = vb0 + (size_t)jt * 2048;
#pragma unroll
        for (int db = 0; db < 2; ++db)
#pragma unroll
            for (int js = 0; js < 2; ++js)
                vf[db][js] = load16(vbc + (db * 2 + js) * 512 + lane * 8);
        // QK[t1][jt] (issue; result read one sigmoid+8 MFMAs later)
        __builtin_amdgcn_s_setprio(1);
        sa1 = f32x16{};
#pragma unroll
        for (int s = 0; s < 4; ++s) sa1 = mfma32(kf[cur][s], qf[1][s], sa1);
        __builtin_amdgcn_s_setprio(0);
        // prefetch K tile jt+2 into kf[cur] (consumed next iter & iter after)
        if (jt < 14) {
            const u16* kbn = kb0 + (size_t)(jt + 2) * 2048;
#pragma unroll
            for (int s = 0; s < 4; ++s) kf[cur][s] = load16(kbn + s * 512 + lane * 8);
        }
        __builtin_amdgcn_sched_barrier(0);
        // sigmoid + pack t0 (sa0 produced last iter -> no MFMA read-stall)
        bf16x8 p00, p01;
        {
            float p[16];
#pragma unroll
            for (int r = 0; r < 16; ++r) {
                float e = __builtin_amdgcn_exp2f(fmaf(sa0[r], c1, c0));
                p[r] = __builtin_amdgcn_rcpf(1.0f + e);
            }
            unsigned wd[8];
#pragma unroll
            for (int u2 = 0; u2 < 8; ++u2) {
                unsigned r_;
                asm("v_cvt_pk_bf16_f32 %0, %1, %2"
                    : "=v"(r_) : "v"(p[2 * u2]), "v"(p[2 * u2 + 1]));
                wd[u2] = r_;
            }
            asm("v_permlane32_swap_b32 %0, %1" : "+v"(wd[0]), "+v"(wd[2]));
            asm("v_permlane32_swap_b32 %0, %1" : "+v"(wd[1]), "+v"(wd[3]));
            asm("v_permlane32_swap_b32 %0, %1" : "+v"(wd[4]), "+v"(wd[6]));
            asm("v_permlane32_swap_b32 %0, %1" : "+v"(wd[5]), "+v"(wd[7]));
            uint4v u0 = {wd[0], wd[1], wd[2], wd[3]};
            uint4v u1 = {wd[4], wd[5], wd[6], wd[7]};
            p00 = __builtin_bit_cast(bf16x8, u0);
            p01 = __builtin_bit_cast(bf16x8, u1);
        }
        __builtin_amdgcn_sched_barrier(0);
        // PV[t0][jt] + QK[t0][jt+1] (issue)
        __builtin_amdgcn_s_setprio(1);
        accO[0][0] = mfma32(vf[0][0], p00, accO[0][0]);
        accO[0][0] = mfma32(vf[0][1], p01, accO[0][0]);
        accO[0][1] = mfma32(vf[1][0], p00, accO[0][1]);
        accO[0][1] = mfma32(vf[1][1], p01, accO[0][1]);
        if (jt < 15) {
            sa0 = f32x16{};
#pragma unroll
            for (int s = 0; s < 4; ++s) sa0 = mfma32(kf[nxt][s], qf[0][s], sa0);
        }
        __builtin_amdgcn_s_setprio(0);
        __builtin_amdgcn_sched_barrier(0);
        // sigmoid + pack t1 (sa1 aged by sigmoid-t0 + 8 MFMAs)
        bf16x8 p10, p11;
        {
            float p[16];
#pragma unroll
            for (int r = 0; r < 16; ++r) {
                float e = __builtin_amdgcn_exp2f(fmaf(sa1[r], c1, c0));
                p[r] = __builtin_amdgcn_rcpf(1.0f + e);
            }
            unsigned wd[8];
#pragma unroll
            for (int u2 = 0; u2 < 8; ++u2) {
                unsigned r_;
                asm("v_cvt_pk_bf16_f32 %0, %1, %2"
                    : "=v"(r_) : "v"(p[2 * u2]), "v"(p[2 * u2 + 1]));
                wd[u2] = r_;
            }
            asm("v_permlane32_swap_b32 %0, %1" : "+v"(wd[0]), "+v"(wd[2]));
            asm("v_permlane32_swap_b32 %0, %1" : "+v"(wd[1]), "+v"(wd[3]));
            asm("v_permlane32_swap_b32 %0, %1" : "+v"(wd[4]), "+v"(wd[6]));
            asm("v_permlane32_swap_b32 %0, %1" : "+v"(wd[5]), "+v"(wd[7]));
            uint4v u0 = {wd[0], wd[1], wd[2], wd[3]};
            uint4v u1 = {wd[4], wd[5], wd[6], wd[7]};
            p10 = __builtin_bit_cast(bf16x8, u0);
            p11 = __builtin_bit_cast(bf16x8, u1);
        }
        __builtin_amdgcn_sched_barrier(0);
        // PV[t1][jt]
        __builtin_amdgcn_s_setprio(1);
        accO[1][0] = mfma32(vf[0][0], p10, accO[1][0]);
        accO[1][0] = mfma32(vf[0][1], p11, accO[1][0]);
        accO[1][1] = mfma32(vf[1][0], p10, accO[1][1]);
        accO[1][1] = mfma32(vf[1][1], p11, accO[1][1]);
        __builtin_amdgcn_s_setprio(0);
    }

    // cross-wave combine (d = db*32 + (r&3)+8(r>>2)+4hi)
    if (jq & 1) {
#pragma unroll
        for (int t = 0; t < 2; ++t)
#pragma unroll
            for (int db = 0; db < 2; ++db)
#pragma unroll
                for (int r = 0; r < 16; ++r)
                    red[jq >> 1][t * 32 + l32][db * 32 + (r & 3) + 8 * (r >> 2) + 4 * hi] =
                        accO[t][db][r];
    }
    __syncthreads();
    if (!(jq & 1)) {
#pragma unroll
        for (int t = 0; t < 2; ++t)
#pragma unroll
            for (int db = 0; db < 2; ++db)
#pragma unroll
                for (int r = 0; r < 16; ++r)
                    accO[t][db][r] +=
                        red[jq >> 1][t * 32 + l32][db * 32 + (r & 3) + 8 * (r >> 2) + 4 * hi];
    }
    __syncthreads();
    if (jq == 2) {
#pragma unroll
        for (int t = 0; t < 2; ++t)
#pragma unroll
            for (int db = 0; db < 2; ++db)
#pragma unroll
                for (int r = 0; r < 16; ++r)
                    red[0][t * 32 + l32][db * 32 + (r & 3) + 8 * (r >> 2) + 4 * hi] =
                        accO[t][db][r];
    }
    __syncthreads();
    if (jq == 0) {
#pragma unroll
        for (int t = 0; t < 2; ++t)
#pragma unroll
            for (int db = 0; db < 2; ++db)
#pragma unroll
                for (int r = 0; r < 16; ++r)
                    accO[t][db][r] +=
                        red[0][t * 32 + l32][db * 32 + (r & 3) + 8 * (r >> 2) + 4 * hi];
#pragma unroll
        for (int t = 0; t < 2; ++t) {
            const int i = it0 * 32 + t * 32 + l32;
#pragma unroll
            for (int db = 0; db < 2; ++db)
#pragma unroll
                for (int q = 0; q < 4; ++q) {
                    int d = db * 32 + 8 * q + 4 * hi;
                    bf16x4 o4;
#pragma unroll
                    for (int r = 0; r < 4; ++r) o4[r] = (__bf16)accO[t][db][4 * q + r];
                    *(bf16x4*)&attn_out[(size_t)(b * NN + i) * 1024 + h * 64 + d] = o4;
                }
        }
    }
}

// ---------------- launch ----------------

extern "C" void kernel_launch(void* const* d_in, const int* in_sizes, int n_in,
                              void* d_out, int out_size, void* d_ws, size_t ws_size,
                              hipStream_t stream) {
    (void)in_sizes; (void)n_in; (void)out_size; (void)ws_size;
    const float* x     = (const float*)d_in[0];
    const float* Wq    = (const float*)d_in[1];
    const float* bq    = (const float*)d_in[2];
    const float* Wk    = (const float*)d_in[3];
    const float* bk    = (const float*)d_in[4];
    const float* Wv    = (const float*)d_in[5];
    const float* bv    = (const float*)d_in[6];
    const float* qn_s  = (const float*)d_in[7];
    const float* qn_b  = (const float*)d_in[8];
    const float* kn_s  = (const float*)d_in[9];
    const float* kn_b  = (const float*)d_in[10];
    const float* ib    = (const float*)d_in[11];
    const float* Wo    = (const float*)d_in[12];
    const float* bo    = (const float*)d_in[13];
    const float* gamma = (const float*)d_in[14];
    float* out = (float*)d_out;

    char* ws = (char*)d_ws;
    size_t off = 0;
    auto alloc = [&](size_t bytes) -> void* {
        void* p = ws + off;
        off += (bytes + 255) & ~(size_t)255;
        return p;
    };
    u16* xb       = (u16*)alloc((size_t)4096 * 1024 * 2);   // x bf16
    u16* wqkv_t   = (u16*)alloc((size_t)3072 * 1024 * 2);   // [n][k]
    u16* wo_t     = (u16*)alloc((size_t)1024 * 1024 * 2);
    u16* Qf       = (u16*)alloc((size_t)32 * 131072 * 2);   // fragment-linear
    u16* Kf       = (u16*)alloc((size_t)32 * 131072 * 2);
    u16* Vf       = (u16*)alloc((size_t)32 * 131072 * 2);
    u16* attn_out = (u16*)alloc((size_t)4096 * 1024 * 2);

    k_prep<<<dim3(32, 32, 5), 256, 0, stream>>>(x, Wq, Wk, Wv, Wo, xb, wqkv_t, wo_t);
    k_gemm_qkv<<<dim3(32, 24), 256, 0, stream>>>(xb, wqkv_t, bq, bk, bv,
                                                 qn_s, qn_b, kn_s, kn_b, Qf, Kf, Vf);
    k_attn<<<1024, 256, 0, stream>>>(Qf, Kf, Vf, ib, attn_out);
    k_gemm_out<<<dim3(32, 8), 256, 0, stream>>>(attn_out, wo_t, bo, gamma, out);
}

// Round 8
// 121.133 us; speedup vs baseline: 1.7698x; 1.0440x over previous
//
#include <hip/hip_runtime.h>

#define DEV static __device__ __forceinline__

typedef __bf16 bf16x8 __attribute__((ext_vector_type(8)));
typedef __bf16 bf16x4 __attribute__((ext_vector_type(4)));
typedef float f32x4 __attribute__((ext_vector_type(4)));
typedef float f32x16 __attribute__((ext_vector_type(16)));
typedef unsigned int uint4v __attribute__((ext_vector_type(4)));
typedef unsigned short ushort4v __attribute__((ext_vector_type(4)));
using u16 = unsigned short;

#define NN 2048
#define DIMD 1024

DEV u16 f2bf(float f) {  // RNE via hardware cvt
    __bf16 b = (__bf16)f;
    return __builtin_bit_cast(u16, b);
}
DEV float bf2f(u16 s) {
    unsigned u = ((unsigned)s) << 16;
    return __builtin_bit_cast(float, u);
}
DEV bf16x8 load16(const u16* p) { return __builtin_bit_cast(bf16x8, *(const uint4v*)p); }
DEV f32x4 mfma16(bf16x8 a, bf16x8 b, f32x4 c) {
    return __builtin_amdgcn_mfma_f32_16x16x32_bf16(a, b, c, 0, 0, 0);
}
DEV f32x16 mfma32(bf16x8 a, bf16x8 b, f32x16 c) {
    return __builtin_amdgcn_mfma_f32_32x32x16_bf16(a, b, c, 0, 0, 0);
}
// async global->LDS, 16B per lane; lds base must be wave-uniform
DEV void gl_lds16(const u16* g, u16* l) {
    __builtin_amdgcn_global_load_lds((const __attribute__((address_space(1))) void*)g,
                                     (__attribute__((address_space(3))) void*)l, 16, 0, 0);
}

// ---------------- prep: W transposes (z<4) + x bf16 pack (z==4) ----------------

__global__ __launch_bounds__(256) void k_prep(const float* __restrict__ x,
                                              const float* __restrict__ s0,
                                              const float* __restrict__ s1,
                                              const float* __restrict__ s2,
                                              const float* __restrict__ s3,
                                              u16* __restrict__ xb,
                                              u16* __restrict__ wqkv_t,
                                              u16* __restrict__ wo_t) {
    __shared__ float tile[32][33];
    const int z = blockIdx.z;
    if (z < 4) {
        const float* src = (z == 0) ? s0 : (z == 1) ? s1 : (z == 2) ? s2 : s3;
        u16* dst = (z < 3) ? (wqkv_t + (size_t)z * 1024 * 1024) : wo_t;
        int tx = threadIdx.x & 31, ty = threadIdx.x >> 5;  // ty 0..7
        int kb = blockIdx.y * 32, nb = blockIdx.x * 32;
#pragma unroll
        for (int j = 0; j < 4; ++j)
            tile[ty + 8 * j][tx] = src[(size_t)(kb + ty + 8 * j) * 1024 + nb + tx];
        __syncthreads();
#pragma unroll
        for (int j = 0; j < 4; ++j)
            dst[(size_t)(nb + ty + 8 * j) * 1024 + kb + tx] = f2bf(tile[tx][ty + 8 * j]);
    } else {
        // pack x: 1,048,576 float4 -> bf16x4; 1024 blocks x 256 thr x 4 each
        const int bidx = blockIdx.y * 32 + blockIdx.x;
#pragma unroll
        for (int q = 0; q < 4; ++q) {
            int i = bidx * 1024 + q * 256 + threadIdx.x;
            float4 v = ((const float4*)x)[i];
            ushort4v o;
            o[0] = f2bf(v.x); o[1] = f2bf(v.y); o[2] = f2bf(v.z); o[3] = f2bf(v.w);
            *(ushort4v*)(xb + (size_t)i * 4) = o;
        }
    }
}

// ---------------- QKV GEMM with fused bias + LayerNorm + fragment-linear write ----------------
// C[m][n] = xb[m][K] * wqkv_t[n][K]^T, K=1024, tile 128x128 (m97 staging).
// Epilogue: cols<2048 -> per-head LN (over d=64) -> Qf/Kf fragment-linear;
//           cols>=2048 -> bias -> Vf fragment-linear.
// Q is additionally scaled by -log2(e) so attn computes exp2(sa + c0) directly.
__global__ __launch_bounds__(256) void k_gemm_qkv(const u16* __restrict__ A,
                                                  const u16* __restrict__ Bt,
                                                  const float* __restrict__ bq,
                                                  const float* __restrict__ bk,
                                                  const float* __restrict__ bv,
                                                  const float* __restrict__ qs,
                                                  const float* __restrict__ qb,
                                                  const float* __restrict__ ks,
                                                  const float* __restrict__ kb_,
                                                  u16* __restrict__ Qf,
                                                  u16* __restrict__ Kf,
                                                  u16* __restrict__ Vf) {
    __shared__ u16 As[128 * 32];
    __shared__ u16 Bs[128 * 32];
    const int K = 1024;
    const int m0 = blockIdx.x * 128, n0 = blockIdx.y * 128;
    const int tid = threadIdx.x;
    const int lane = tid & 63, w = tid >> 6;
    const int wr = w >> 1, wc = w & 1;
    const int li = lane & 15, g = lane >> 4;

    f32x4 acc[4][4] = {};

    const u16* gA = A + (size_t)(m0 + w * 16 + (lane >> 2)) * K + (lane & 3) * 8;
    const u16* gB = Bt + (size_t)(n0 + w * 16 + (lane >> 2)) * K + (lane & 3) * 8;
    u16* lA = &As[(w * 16) * 32];
    u16* lB = &Bs[(w * 16) * 32];

    for (int k0 = 0; k0 < K; k0 += 32) {
        __syncthreads();
        gl_lds16(gA + k0, lA);
        gl_lds16(gA + (size_t)64 * K + k0, lA + 64 * 32);
        gl_lds16(gB + k0, lB);
        gl_lds16(gB + (size_t)64 * K + k0, lB + 64 * 32);
        asm volatile("s_waitcnt vmcnt(0)" ::: "memory");
        __syncthreads();
        bf16x8 af[4], bfv[4];
#pragma unroll
        for (int mi = 0; mi < 4; ++mi)
            af[mi] = load16(&As[(wr * 64 + mi * 16 + li) * 32 + g * 8]);
#pragma unroll
        for (int ni = 0; ni < 4; ++ni)
            bfv[ni] = load16(&Bs[(wc * 64 + ni * 16 + li) * 32 + g * 8]);
#pragma unroll
        for (int mi = 0; mi < 4; ++mi)
#pragma unroll
            for (int ni = 0; ni < 4; ++ni)
                acc[mi][ni] = mfma16(af[mi], bfv[ni], acc[mi][ni]);
    }

    // ---- fused epilogue ----
    const int col0 = n0 + wc * 64;        // 64-aligned head segment base
    const int seg = col0 >> 10;           // 0=q, 1=k, 2=v
    const int hcol = col0 & 1023;         // col base within its matrix
    const int h = hcol >> 6;

    if (seg < 2) {
        const float* S = (seg == 0) ? qs : ks;
        const float* Bb = (seg == 0) ? qb : kb_;
        const float* bias = (seg == 0) ? bq : bk;
        u16* dst = (seg == 0) ? Qf : Kf;
        const float sc = (seg == 0) ? -1.44269504f : 1.0f;  // fold -log2e into Q
        float lnS[4], lnB[4], bv4[4];
#pragma unroll
        for (int ni = 0; ni < 4; ++ni) {
            int d = ni * 16 + li;
            lnS[ni] = S[d] * sc; lnB[ni] = Bb[d] * sc; bv4[ni] = bias[hcol + d];
        }
#pragma unroll
        for (int mi = 0; mi < 4; ++mi) {
#pragma unroll
            for (int r = 0; r < 4; ++r) {
                float v0 = acc[mi][0][r] + bv4[0];
                float v1 = acc[mi][1][r] + bv4[1];
                float v2 = acc[mi][2][r] + bv4[2];
                float v3 = acc[mi][3][r] + bv4[3];
                float s1 = v0 + v1 + v2 + v3;
                float s2 = v0 * v0 + v1 * v1 + v2 * v2 + v3 * v3;
#pragma unroll
                for (int o = 1; o < 16; o <<= 1) {
                    s1 += __shfl_xor(s1, o);
                    s2 += __shfl_xor(s2, o);
                }
                float mu = s1 * (1.0f / 64.0f);
                float var = s2 * (1.0f / 64.0f) - mu * mu;
                float rsv = rsqrtf(var + 1e-6f);
                int row = m0 + wr * 64 + mi * 16 + 4 * g + r;
                int bseq = row >> 11, n = row & 2047;
                size_t base = ((size_t)(bseq * 16 + h)) * 131072 +
                              ((size_t)(n >> 5) * 4) * 512 + (size_t)(n & 31) * 8 +
                              (li >> 3) * 256 + (li & 7);
                dst[base + 0 * 512] = f2bf((v0 - mu) * rsv * lnS[0] + lnB[0]);
                dst[base + 1 * 512] = f2bf((v1 - mu) * rsv * lnS[1] + lnB[1]);
                dst[base + 2 * 512] = f2bf((v2 - mu) * rsv * lnS[2] + lnB[2]);
                dst[base + 3 * 512] = f2bf((v3 - mu) * rsv * lnS[3] + lnB[3]);
            }
        }
    } else {
        float bv4[4];
#pragma unroll
        for (int ni = 0; ni < 4; ++ni) bv4[ni] = bv[hcol + ni * 16 + li];
#pragma unroll
        for (int mi = 0; mi < 4; ++mi) {
#pragma unroll
            for (int r = 0; r < 4; ++r) {
                int row = m0 + wr * 64 + mi * 16 + 4 * g + r;
                int bseq = row >> 11, j = row & 2047;
                size_t vb_ = ((size_t)(bseq * 16 + h)) * 131072 +
                             ((size_t)((j >> 5) * 4 + ((j >> 4) & 1))) * 512 +
                             (size_t)(((j >> 3) & 1) * 32) * 8 + (j & 7);
#pragma unroll
                for (int ni = 0; ni < 4; ++ni)
                    Vf[vb_ + (ni >> 1) * 1024 + ((ni & 1) * 16 + li) * 8] =
                        f2bf(acc[mi][ni][r] + bv4[ni]);
            }
        }
    }
}

// ---------------- output GEMM: out fp32 = (acc + bo[n]) * gamma[n] ----------------
// 128x64 tile -> grid 32x16 = 512 blocks (2/CU) for occupancy.
__global__ __launch_bounds__(256) void k_gemm_out(const u16* __restrict__ A,
                                                  const u16* __restrict__ Bt,
                                                  const float* __restrict__ bias,
                                                  const float* __restrict__ gamma,
                                                  float* __restrict__ out) {
    __shared__ u16 As[128 * 32];
    __shared__ u16 Bs[64 * 32];
    const int K = 1024, ldc = 1024;
    const int m0 = blockIdx.x * 128, n0 = blockIdx.y * 64;
    const int tid = threadIdx.x;
    const int lane = tid & 63, w = tid >> 6;
    const int wr = w >> 1, wc = w & 1;
    const int li = lane & 15, g = lane >> 4;

    f32x4 acc[4][2] = {};

    const u16* gA = A + (size_t)(m0 + w * 16 + (lane >> 2)) * K + (lane & 3) * 8;
    const u16* gB = Bt + (size_t)(n0 + w * 16 + (lane >> 2)) * K + (lane & 3) * 8;
    u16* lA = &As[(w * 16) * 32];
    u16* lB = &Bs[(w * 16) * 32];

    for (int k0 = 0; k0 < K; k0 += 32) {
        __syncthreads();
        gl_lds16(gA + k0, lA);
        gl_lds16(gA + (size_t)64 * K + k0, lA + 64 * 32);
        gl_lds16(gB + k0, lB);  // 64 rows total across 4 waves
        asm volatile("s_waitcnt vmcnt(0)" ::: "memory");
        __syncthreads();
        bf16x8 af[4], bfv[2];
#pragma unroll
        for (int mi = 0; mi < 4; ++mi)
            af[mi] = load16(&As[(wr * 64 + mi * 16 + li) * 32 + g * 8]);
#pragma unroll
        for (int ni = 0; ni < 2; ++ni)
            bfv[ni] = load16(&Bs[(wc * 32 + ni * 16 + li) * 32 + g * 8]);
#pragma unroll
        for (int mi = 0; mi < 4; ++mi)
#pragma unroll
            for (int ni = 0; ni < 2; ++ni)
                acc[mi][ni] = mfma16(af[mi], bfv[ni], acc[mi][ni]);
    }

#pragma unroll
    for (int mi = 0; mi < 4; ++mi) {
        int row = m0 + wr * 64 + mi * 16 + 4 * g;
#pragma unroll
        for (int ni = 0; ni < 2; ++ni) {
            int col = n0 + wc * 32 + ni * 16 + li;
            float bv_ = bias[col], gv = gamma[col];
            f32x4 v = acc[mi][ni];
#pragma unroll
            for (int r = 0; r < 4; ++r)
                out[(size_t)(row + r) * ldc + col] = (v[r] + bv_) * gv;
        }
    }
}

// ---------------- fused sigmoid attention v8 ----------------
// v7 ping-pong structure + (a) fma-free sigmoid: Q pre-scaled by -log2e and
// QK accumulator initialized to c0 = -bias*log2e so arg = sa directly;
// (b) #pragma unroll 2 (I-cache: body was ~30KB fully unrolled).
__global__ __launch_bounds__(256, 2) void k_attn(const u16* __restrict__ Qf,
                                                 const u16* __restrict__ Kf,
                                                 const u16* __restrict__ Vf,
                                                 const float* __restrict__ ib,
                                                 u16* __restrict__ attn_out) {
    __shared__ float red[2][64][65];
    const int bid = blockIdx.x;
    const int xcd = bid & 7, idx = bid >> 3;  // 1024 blocks: 128 per XCD
    const int bh = xcd * 4 + (idx >> 5);      // 4 bh per XCD -> K/V L2-resident
    const int iblk = idx & 31;
    const int b = bh >> 4, h = bh & 15;
    const int tid = threadIdx.x;
    const int jq = tid >> 6, lane = tid & 63;
    const int l32 = lane & 31, hi = lane >> 5;
    const float c0 = -ib[0] * 1.44269504f;  // exp2(sa + 0) with sa pre-scaled; init acc = c0
    const u16* Qb = Qf + (size_t)bh * 131072;
    const u16* Kb = Kf + (size_t)bh * 131072;
    const u16* Vb = Vf + (size_t)bh * 131072;
    const int it0 = iblk * 2;

    bf16x8 qf[2][4];
#pragma unroll
    for (int t = 0; t < 2; ++t)
#pragma unroll
        for (int s = 0; s < 4; ++s)
            qf[t][s] = load16(Qb + ((size_t)((it0 + t) * 4 + s)) * 512 + lane * 8);

    f32x16 accO[2][2] = {};
    const u16* kb0 = Kb + (size_t)(jq * 16) * 2048;
    const u16* vb0 = Vb + (size_t)(jq * 16) * 2048;

    f32x16 cinit;
#pragma unroll
    for (int r = 0; r < 16; ++r) cinit[r] = c0;

    // prologue: K tiles 0,1; QK[t0][0]
    bf16x8 kf[2][4];
#pragma unroll
    for (int s = 0; s < 4; ++s) kf[0][s] = load16(kb0 + s * 512 + lane * 8);
#pragma unroll
    for (int s = 0; s < 4; ++s) kf[1][s] = load16(kb0 + 2048 + s * 512 + lane * 8);
    f32x16 sa0 = cinit, sa1;
#pragma unroll
    for (int s = 0; s < 4; ++s) sa0 = mfma32(kf[0][s], qf[0][s], sa0);

#pragma unroll 2
    for (int jt = 0; jt < 16; ++jt) {
        const int cur = jt & 1, nxt = cur ^ 1;
        // V fragments for this jt (consumed by PV below; latency under QK issue)
        bf16x8 vf[2][2];
        const u16* vbc = vb0 + (size_t)jt * 2048;
#pragma unroll
        for (int db = 0; db < 2; ++db)
#pragma unroll
            for (int js = 0; js < 2; ++js)
                vf[db][js] = load16(vbc + (db * 2 + js) * 512 + lane * 8);
        // QK[t1][jt] (issue; result read one sigmoid+8 MFMAs later)
        __builtin_amdgcn_s_setprio(1);
        sa1 = cinit;
#pragma unroll
        for (int s = 0; s < 4; ++s) sa1 = mfma32(kf[cur][s], qf[1][s], sa1);
        __builtin_amdgcn_s_setprio(0);
        // prefetch K tile jt+2 into kf[cur] (consumed next iter & iter after)
        if (jt < 14) {
            const u16* kbn = kb0 + (size_t)(jt + 2) * 2048;
#pragma unroll
            for (int s = 0; s < 4; ++s) kf[cur][s] = load16(kbn + s * 512 + lane * 8);
        }
        __builtin_amdgcn_sched_barrier(0);
        // sigmoid + pack t0 (sa0 produced last iter -> no MFMA read-stall)
        bf16x8 p00, p01;
        {
            float p[16];
#pragma unroll
            for (int r = 0; r < 16; ++r) {
                float e = __builtin_amdgcn_exp2f(sa0[r]);
                p[r] = __builtin_amdgcn_rcpf(1.0f + e);
            }
            unsigned wd[8];
#pragma unroll
            for (int u2 = 0; u2 < 8; ++u2) {
                unsigned r_;
                asm("v_cvt_pk_bf16_f32 %0, %1, %2"
                    : "=v"(r_) : "v"(p[2 * u2]), "v"(p[2 * u2 + 1]));
                wd[u2] = r_;
            }
            asm("v_permlane32_swap_b32 %0, %1" : "+v"(wd[0]), "+v"(wd[2]));
            asm("v_permlane32_swap_b32 %0, %1" : "+v"(wd[1]), "+v"(wd[3]));
            asm("v_permlane32_swap_b32 %0, %1" : "+v"(wd[4]), "+v"(wd[6]));
            asm("v_permlane32_swap_b32 %0, %1" : "+v"(wd[5]), "+v"(wd[7]));
            uint4v u0 = {wd[0], wd[1], wd[2], wd[3]};
            uint4v u1 = {wd[4], wd[5], wd[6], wd[7]};
            p00 = __builtin_bit_cast(bf16x8, u0);
            p01 = __builtin_bit_cast(bf16x8, u1);
        }
        __builtin_amdgcn_sched_barrier(0);
        // PV[t0][jt] + QK[t0][jt+1] (issue)
        __builtin_amdgcn_s_setprio(1);
        accO[0][0] = mfma32(vf[0][0], p00, accO[0][0]);
        accO[0][0] = mfma32(vf[0][1], p01, accO[0][0]);
        accO[0][1] = mfma32(vf[1][0], p00, accO[0][1]);
        accO[0][1] = mfma32(vf[1][1], p01, accO[0][1]);
        if (jt < 15) {
            sa0 = cinit;
#pragma unroll
            for (int s = 0; s < 4; ++s) sa0 = mfma32(kf[nxt][s], qf[0][s], sa0);
        }
        __builtin_amdgcn_s_setprio(0);
        __builtin_amdgcn_sched_barrier(0);
        // sigmoid + pack t1 (sa1 aged by sigmoid-t0 + 8 MFMAs)
        bf16x8 p10, p11;
        {
            float p[16];
#pragma unroll
            for (int r = 0; r < 16; ++r) {
                float e = __builtin_amdgcn_exp2f(sa1[r]);
                p[r] = __builtin_amdgcn_rcpf(1.0f + e);
            }
            unsigned wd[8];
#pragma unroll
            for (int u2 = 0; u2 < 8; ++u2) {
                unsigned r_;
                asm("v_cvt_pk_bf16_f32 %0, %1, %2"
                    : "=v"(r_) : "v"(p[2 * u2]), "v"(p[2 * u2 + 1]));
                wd[u2] = r_;
            }
            asm("v_permlane32_swap_b32 %0, %1" : "+v"(wd[0]), "+v"(wd[2]));
            asm("v_permlane32_swap_b32 %0, %1" : "+v"(wd[1]), "+v"(wd[3]));
            asm("v_permlane32_swap_b32 %0, %1" : "+v"(wd[4]), "+v"(wd[6]));
            asm("v_permlane32_swap_b32 %0, %1" : "+v"(wd[5]), "+v"(wd[7]));
            uint4v u0 = {wd[0], wd[1], wd[2], wd[3]};
            uint4v u1 = {wd[4], wd[5], wd[6], wd[7]};
            p10 = __builtin_bit_cast(bf16x8, u0);
            p11 = __builtin_bit_cast(bf16x8, u1);
        }
        __builtin_amdgcn_sched_barrier(0);
        // PV[t1][jt]
        __builtin_amdgcn_s_setprio(1);
        accO[1][0] = mfma32(vf[0][0], p10, accO[1][0]);
        accO[1][0] = mfma32(vf[0][1], p11, accO[1][0]);
        accO[1][1] = mfma32(vf[1][0], p10, accO[1][1]);
        accO[1][1] = mfma32(vf[1][1], p11, accO[1][1]);
        __builtin_amdgcn_s_setprio(0);
    }

    // cross-wave combine (d = db*32 + (r&3)+8(r>>2)+4hi)
    if (jq & 1) {
#pragma unroll
        for (int t = 0; t < 2; ++t)
#pragma unroll
            for (int db = 0; db < 2; ++db)
#pragma unroll
                for (int r = 0; r < 16; ++r)
                    red[jq >> 1][t * 32 + l32][db * 32 + (r & 3) + 8 * (r >> 2) + 4 * hi] =
                        accO[t][db][r];
    }
    __syncthreads();
    if (!(jq & 1)) {
#pragma unroll
        for (int t = 0; t < 2; ++t)
#pragma unroll
            for (int db = 0; db < 2; ++db)
#pragma unroll
                for (int r = 0; r < 16; ++r)
                    accO[t][db][r] +=
                        red[jq >> 1][t * 32 + l32][db * 32 + (r & 3) + 8 * (r >> 2) + 4 * hi];
    }
    __syncthreads();
    if (jq == 2) {
#pragma unroll
        for (int t = 0; t < 2; ++t)
#pragma unroll
            for (int db = 0; db < 2; ++db)
#pragma unroll
                for (int r = 0; r < 16; ++r)
                    red[0][t * 32 + l32][db * 32 + (r & 3) + 8 * (r >> 2) + 4 * hi] =
                        accO[t][db][r];
    }
    __syncthreads();
    if (jq == 0) {
#pragma unroll
        for (int t = 0; t < 2; ++t)
#pragma unroll
            for (int db = 0; db < 2; ++db)
#pragma unroll
                for (int r = 0; r < 16; ++r)
                    accO[t][db][r] +=
                        red[0][t * 32 + l32][db * 32 + (r & 3) + 8 * (r >> 2) + 4 * hi];
#pragma unroll
        for (int t = 0; t < 2; ++t) {
            const int i = it0 * 32 + t * 32 + l32;
#pragma unroll
            for (int db = 0; db < 2; ++db)
#pragma unroll
                for (int q = 0; q < 4; ++q) {
                    int d = db * 32 + 8 * q + 4 * hi;
                    bf16x4 o4;
#pragma unroll
                    for (int r = 0; r < 4; ++r) o4[r] = (__bf16)accO[t][db][4 * q + r];
                    *(bf16x4*)&attn_out[(size_t)(b * NN + i) * 1024 + h * 64 + d] = o4;
                }
        }
    }
}

// ---------------- launch ----------------

extern "C" void kernel_launch(void* const* d_in, const int* in_sizes, int n_in,
                              void* d_out, int out_size, void* d_ws, size_t ws_size,
                              hipStream_t stream) {
    (void)in_sizes; (void)n_in; (void)out_size; (void)ws_size;
    const float* x     = (const float*)d_in[0];
    const float* Wq    = (const float*)d_in[1];
    const float* bq    = (const float*)d_in[2];
    const float* Wk    = (const float*)d_in[3];
    const float* bk    = (const float*)d_in[4];
    const float* Wv    = (const float*)d_in[5];
    const float* bv    = (const float*)d_in[6];
    const float* qn_s  = (const float*)d_in[7];
    const float* qn_b  = (const float*)d_in[8];
    const float* kn_s  = (const float*)d_in[9];
    const float* kn_b  = (const float*)d_in[10];
    const float* ib    = (const float*)d_in[11];
    const float* Wo    = (const float*)d_in[12];
    const float* bo    = (const float*)d_in[13];
    const float* gamma = (const float*)d_in[14];
    float* out = (float*)d_out;

    char* ws = (char*)d_ws;
    size_t off = 0;
    auto alloc = [&](size_t bytes) -> void* {
        void* p = ws + off;
        off += (bytes + 255) & ~(size_t)255;
        return p;
    };
    u16* xb       = (u16*)alloc((size_t)4096 * 1024 * 2);   // x bf16
    u16* wqkv_t   = (u16*)alloc((size_t)3072 * 1024 * 2);   // [n][k]
    u16* wo_t     = (u16*)alloc((size_t)1024 * 1024 * 2);
    u16* Qf       = (u16*)alloc((size_t)32 * 131072 * 2);   // fragment-linear
    u16* Kf       = (u16*)alloc((size_t)32 * 131072 * 2);
    u16* Vf       = (u16*)alloc((size_t)32 * 131072 * 2);
    u16* attn_out = (u16*)alloc((size_t)4096 * 1024 * 2);

    k_prep<<<dim3(32, 32, 5), 256, 0, stream>>>(x, Wq, Wk, Wv, Wo, xb, wqkv_t, wo_t);
    k_gemm_qkv<<<dim3(32, 24), 256, 0, stream>>>(xb, wqkv_t, bq, bk, bv,
                                                 qn_s, qn_b, kn_s, kn_b, Qf, Kf, Vf);
    k_attn<<<1024, 256, 0, stream>>>(Qf, Kf, Vf, ib, attn_out);
    k_gemm_out<<<dim3(32, 16), 256, 0, stream>>>(attn_out, wo_t, bo, gamma, out);
}

// Round 9
// 116.061 us; speedup vs baseline: 1.8471x; 1.0437x over previous
//
#include <hip/hip_runtime.h>

#define DEV static __device__ __forceinline__

typedef __bf16 bf16x8 __attribute__((ext_vector_type(8)));
typedef __bf16 bf16x4 __attribute__((ext_vector_type(4)));
typedef float f32x4 __attribute__((ext_vector_type(4)));
typedef float f32x16 __attribute__((ext_vector_type(16)));
typedef unsigned int uint4v __attribute__((ext_vector_type(4)));
typedef unsigned short ushort4v __attribute__((ext_vector_type(4)));
using u16 = unsigned short;

#define NN 2048
#define DIMD 1024

DEV u16 f2bf(float f) {  // RNE via hardware cvt
    __bf16 b = (__bf16)f;
    return __builtin_bit_cast(u16, b);
}
DEV float bf2f(u16 s) {
    unsigned u = ((unsigned)s) << 16;
    return __builtin_bit_cast(float, u);
}
DEV bf16x8 load16(const u16* p) { return __builtin_bit_cast(bf16x8, *(const uint4v*)p); }
DEV f32x4 mfma16(bf16x8 a, bf16x8 b, f32x4 c) {
    return __builtin_amdgcn_mfma_f32_16x16x32_bf16(a, b, c, 0, 0, 0);
}
DEV f32x16 mfma32(bf16x8 a, bf16x8 b, f32x16 c) {
    return __builtin_amdgcn_mfma_f32_32x32x16_bf16(a, b, c, 0, 0, 0);
}
// async global->LDS, 16B per lane; lds base must be wave-uniform
DEV void gl_lds16(const u16* g, u16* l) {
    __builtin_amdgcn_global_load_lds((const __attribute__((address_space(1))) void*)g,
                                     (__attribute__((address_space(3))) void*)l, 16, 0, 0);
}

// ---------------- prep: W transposes (z<4) + x bf16 pack (z==4) ----------------

__global__ __launch_bounds__(256) void k_prep(const float* __restrict__ x,
                                              const float* __restrict__ s0,
                                              const float* __restrict__ s1,
                                              const float* __restrict__ s2,
                                              const float* __restrict__ s3,
                                              u16* __restrict__ xb,
                                              u16* __restrict__ wqkv_t,
                                              u16* __restrict__ wo_t) {
    __shared__ float tile[32][33];
    const int z = blockIdx.z;
    if (z < 4) {
        const float* src = (z == 0) ? s0 : (z == 1) ? s1 : (z == 2) ? s2 : s3;
        u16* dst = (z < 3) ? (wqkv_t + (size_t)z * 1024 * 1024) : wo_t;
        int tx = threadIdx.x & 31, ty = threadIdx.x >> 5;  // ty 0..7
        int kb = blockIdx.y * 32, nb = blockIdx.x * 32;
#pragma unroll
        for (int j = 0; j < 4; ++j)
            tile[ty + 8 * j][tx] = src[(size_t)(kb + ty + 8 * j) * 1024 + nb + tx];
        __syncthreads();
#pragma unroll
        for (int j = 0; j < 4; ++j)
            dst[(size_t)(nb + ty + 8 * j) * 1024 + kb + tx] = f2bf(tile[tx][ty + 8 * j]);
    } else {
        // pack x: 1,048,576 float4 -> bf16x4; 1024 blocks x 256 thr x 4 each
        const int bidx = blockIdx.y * 32 + blockIdx.x;
#pragma unroll
        for (int q = 0; q < 4; ++q) {
            int i = bidx * 1024 + q * 256 + threadIdx.x;
            float4 v = ((const float4*)x)[i];
            ushort4v o;
            o[0] = f2bf(v.x); o[1] = f2bf(v.y); o[2] = f2bf(v.z); o[3] = f2bf(v.w);
            *(ushort4v*)(xb + (size_t)i * 4) = o;
        }
    }
}

// ---------------- QKV GEMM: BK=64, XOR-swizzled LDS, fused LN epilogue ----------------
// C[m][n] = xb[m][K] * wqkv_t[n][K]^T, K=1024, tile 128x128, BK=64.
// LDS: [128 rows][8 chunks of 16B]; slot (r, c') holds global chunk c'^(r&7)
// (achieved by pre-swizzling the per-lane global source column; gl_lds dest
// stays linear). ds_read chunk for (s,g) = (s*4+g)^(li&7) -> 2-way banks (free).
// Epilogue: cols<2048 -> per-head LN -> Qf/Kf fragment-linear (Q scaled -log2e);
//           cols>=2048 -> bias -> Vf fragment-linear.
__global__ __launch_bounds__(256) void k_gemm_qkv(const u16* __restrict__ A,
                                                  const u16* __restrict__ Bt,
                                                  const float* __restrict__ bq,
                                                  const float* __restrict__ bk,
                                                  const float* __restrict__ bv,
                                                  const float* __restrict__ qs,
                                                  const float* __restrict__ qb,
                                                  const float* __restrict__ ks,
                                                  const float* __restrict__ kb_,
                                                  u16* __restrict__ Qf,
                                                  u16* __restrict__ Kf,
                                                  u16* __restrict__ Vf) {
    __shared__ u16 As[128 * 64];  // 16KB
    __shared__ u16 Bs[128 * 64];  // 16KB
    const int K = 1024;
    const int m0 = blockIdx.x * 128, n0 = blockIdx.y * 128;
    const int tid = threadIdx.x;
    const int lane = tid & 63, w = tid >> 6;
    const int wr = w >> 1, wc = w & 1;
    const int li = lane & 15, g = lane >> 4;
    const int l7 = li & 7;

    f32x4 acc[4][4] = {};

    // staging: lane covers row w*8 + (lane>>3) (+32*i), source chunk swizzled
    const int lr = lane >> 3;
    const int lc = (lane & 7) ^ lr;
    const u16* gA = A + (size_t)(m0 + w * 8 + lr) * K + lc * 8;
    const u16* gB = Bt + (size_t)(n0 + w * 8 + lr) * K + lc * 8;
    u16* lA = &As[w * 512];
    u16* lB = &Bs[w * 512];

    for (int k0 = 0; k0 < K; k0 += 64) {
        __syncthreads();
#pragma unroll
        for (int i = 0; i < 4; ++i) {
            gl_lds16(gA + (size_t)(i * 32) * K + k0, lA + i * 2048);
            gl_lds16(gB + (size_t)(i * 32) * K + k0, lB + i * 2048);
        }
        asm volatile("s_waitcnt vmcnt(0)" ::: "memory");
        __syncthreads();
        bf16x8 af[4][2], bfv[4][2];
#pragma unroll
        for (int mi = 0; mi < 4; ++mi) {
            const int row = wr * 64 + mi * 16 + li;
#pragma unroll
            for (int s = 0; s < 2; ++s)
                af[mi][s] = load16(&As[row * 64 + (((s * 4 + g) ^ l7) * 8)]);
        }
#pragma unroll
        for (int ni = 0; ni < 4; ++ni) {
            const int row = wc * 64 + ni * 16 + li;
#pragma unroll
            for (int s = 0; s < 2; ++s)
                bfv[ni][s] = load16(&Bs[row * 64 + (((s * 4 + g) ^ l7) * 8)]);
        }
#pragma unroll
        for (int mi = 0; mi < 4; ++mi)
#pragma unroll
            for (int ni = 0; ni < 4; ++ni) {
                acc[mi][ni] = mfma16(af[mi][0], bfv[ni][0], acc[mi][ni]);
                acc[mi][ni] = mfma16(af[mi][1], bfv[ni][1], acc[mi][ni]);
            }
    }

    // ---- fused epilogue ----
    const int col0 = n0 + wc * 64;        // 64-aligned head segment base
    const int seg = col0 >> 10;           // 0=q, 1=k, 2=v
    const int hcol = col0 & 1023;         // col base within its matrix
    const int h = hcol >> 6;

    if (seg < 2) {
        const float* S = (seg == 0) ? qs : ks;
        const float* Bb = (seg == 0) ? qb : kb_;
        const float* bias = (seg == 0) ? bq : bk;
        u16* dst = (seg == 0) ? Qf : Kf;
        const float sc = (seg == 0) ? -1.44269504f : 1.0f;  // fold -log2e into Q
        float lnS[4], lnB[4], bv4[4];
#pragma unroll
        for (int ni = 0; ni < 4; ++ni) {
            int d = ni * 16 + li;
            lnS[ni] = S[d] * sc; lnB[ni] = Bb[d] * sc; bv4[ni] = bias[hcol + d];
        }
#pragma unroll
        for (int mi = 0; mi < 4; ++mi) {
#pragma unroll
            for (int r = 0; r < 4; ++r) {
                float v0 = acc[mi][0][r] + bv4[0];
                float v1 = acc[mi][1][r] + bv4[1];
                float v2 = acc[mi][2][r] + bv4[2];
                float v3 = acc[mi][3][r] + bv4[3];
                float s1 = v0 + v1 + v2 + v3;
                float s2 = v0 * v0 + v1 * v1 + v2 * v2 + v3 * v3;
#pragma unroll
                for (int o = 1; o < 16; o <<= 1) {
                    s1 += __shfl_xor(s1, o);
                    s2 += __shfl_xor(s2, o);
                }
                float mu = s1 * (1.0f / 64.0f);
                float var = s2 * (1.0f / 64.0f) - mu * mu;
                float rsv = rsqrtf(var + 1e-6f);
                int row = m0 + wr * 64 + mi * 16 + 4 * g + r;
                int bseq = row >> 11, n = row & 2047;
                size_t base = ((size_t)(bseq * 16 + h)) * 131072 +
                              ((size_t)(n >> 5) * 4) * 512 + (size_t)(n & 31) * 8 +
                              (li >> 3) * 256 + (li & 7);
                dst[base + 0 * 512] = f2bf((v0 - mu) * rsv * lnS[0] + lnB[0]);
                dst[base + 1 * 512] = f2bf((v1 - mu) * rsv * lnS[1] + lnB[1]);
                dst[base + 2 * 512] = f2bf((v2 - mu) * rsv * lnS[2] + lnB[2]);
                dst[base + 3 * 512] = f2bf((v3 - mu) * rsv * lnS[3] + lnB[3]);
            }
        }
    } else {
        float bv4[4];
#pragma unroll
        for (int ni = 0; ni < 4; ++ni) bv4[ni] = bv[hcol + ni * 16 + li];
#pragma unroll
        for (int mi = 0; mi < 4; ++mi) {
#pragma unroll
            for (int r = 0; r < 4; ++r) {
                int row = m0 + wr * 64 + mi * 16 + 4 * g + r;
                int bseq = row >> 11, j = row & 2047;
                size_t vb_ = ((size_t)(bseq * 16 + h)) * 131072 +
                             ((size_t)((j >> 5) * 4 + ((j >> 4) & 1))) * 512 +
                             (size_t)(((j >> 3) & 1) * 32) * 8 + (j & 7);
#pragma unroll
                for (int ni = 0; ni < 4; ++ni)
                    Vf[vb_ + (ni >> 1) * 1024 + ((ni & 1) * 16 + li) * 8] =
                        f2bf(acc[mi][ni][r] + bv4[ni]);
            }
        }
    }
}

// ---------------- output GEMM: BK=64 + swizzle; out fp32 = (acc+bo)*gamma ----------------
// 128x64 tile -> grid 32x16 = 512 blocks (2/CU).
__global__ __launch_bounds__(256) void k_gemm_out(const u16* __restrict__ A,
                                                  const u16* __restrict__ Bt,
                                                  const float* __restrict__ bias,
                                                  const float* __restrict__ gamma,
                                                  float* __restrict__ out) {
    __shared__ u16 As[128 * 64];  // 16KB
    __shared__ u16 Bs[64 * 64];   // 8KB
    const int K = 1024, ldc = 1024;
    const int m0 = blockIdx.x * 128, n0 = blockIdx.y * 64;
    const int tid = threadIdx.x;
    const int lane = tid & 63, w = tid >> 6;
    const int wr = w >> 1, wc = w & 1;
    const int li = lane & 15, g = lane >> 4;
    const int l7 = li & 7;

    f32x4 acc[4][2] = {};

    const int lr = lane >> 3;
    const int lc = (lane & 7) ^ lr;
    const u16* gA = A + (size_t)(m0 + w * 8 + lr) * K + lc * 8;
    const u16* gB = Bt + (size_t)(n0 + w * 8 + lr) * K + lc * 8;
    u16* lA = &As[w * 512];
    u16* lB = &Bs[w * 512];

    for (int k0 = 0; k0 < K; k0 += 64) {
        __syncthreads();
#pragma unroll
        for (int i = 0; i < 4; ++i)
            gl_lds16(gA + (size_t)(i * 32) * K + k0, lA + i * 2048);
#pragma unroll
        for (int i = 0; i < 2; ++i)
            gl_lds16(gB + (size_t)(i * 32) * K + k0, lB + i * 2048);
        asm volatile("s_waitcnt vmcnt(0)" ::: "memory");
        __syncthreads();
        bf16x8 af[4][2], bfv[2][2];
#pragma unroll
        for (int mi = 0; mi < 4; ++mi) {
            const int row = wr * 64 + mi * 16 + li;
#pragma unroll
            for (int s = 0; s < 2; ++s)
                af[mi][s] = load16(&As[row * 64 + (((s * 4 + g) ^ l7) * 8)]);
        }
#pragma unroll
        for (int ni = 0; ni < 2; ++ni) {
            const int row = wc * 32 + ni * 16 + li;
#pragma unroll
            for (int s = 0; s < 2; ++s)
                bfv[ni][s] = load16(&Bs[row * 64 + (((s * 4 + g) ^ l7) * 8)]);
        }
#pragma unroll
        for (int mi = 0; mi < 4; ++mi)
#pragma unroll
            for (int ni = 0; ni < 2; ++ni) {
                acc[mi][ni] = mfma16(af[mi][0], bfv[ni][0], acc[mi][ni]);
                acc[mi][ni] = mfma16(af[mi][1], bfv[ni][1], acc[mi][ni]);
            }
    }

#pragma unroll
    for (int mi = 0; mi < 4; ++mi) {
        int row = m0 + wr * 64 + mi * 16 + 4 * g;
#pragma unroll
        for (int ni = 0; ni < 2; ++ni) {
            int col = n0 + wc * 32 + ni * 16 + li;
            float bv_ = bias[col], gv = gamma[col];
            f32x4 v = acc[mi][ni];
#pragma unroll
            for (int r = 0; r < 4; ++r)
                out[(size_t)(row + r) * ldc + col] = (v[r] + bv_) * gv;
        }
    }
}

// ---------------- fused sigmoid attention v8 (unchanged from round 8) ----------------
__global__ __launch_bounds__(256, 2) void k_attn(const u16* __restrict__ Qf,
                                                 const u16* __restrict__ Kf,
                                                 const u16* __restrict__ Vf,
                                                 const float* __restrict__ ib,
                                                 u16* __restrict__ attn_out) {
    __shared__ float red[2][64][65];
    const int bid = blockIdx.x;
    const int xcd = bid & 7, idx = bid >> 3;  // 1024 blocks: 128 per XCD
    const int bh = xcd * 4 + (idx >> 5);      // 4 bh per XCD -> K/V L2-resident
    const int iblk = idx & 31;
    const int b = bh >> 4, h = bh & 15;
    const int tid = threadIdx.x;
    const int jq = tid >> 6, lane = tid & 63;
    const int l32 = lane & 31, hi = lane >> 5;
    const float c0 = -ib[0] * 1.44269504f;  // acc init; Q pre-scaled by -log2e
    const u16* Qb = Qf + (size_t)bh * 131072;
    const u16* Kb = Kf + (size_t)bh * 131072;
    const u16* Vb = Vf + (size_t)bh * 131072;
    const int it0 = iblk * 2;

    bf16x8 qf[2][4];
#pragma unroll
    for (int t = 0; t < 2; ++t)
#pragma unroll
        for (int s = 0; s < 4; ++s)
            qf[t][s] = load16(Qb + ((size_t)((it0 + t) * 4 + s)) * 512 + lane * 8);

    f32x16 accO[2][2] = {};
    const u16* kb0 = Kb + (size_t)(jq * 16) * 2048;
    const u16* vb0 = Vb + (size_t)(jq * 16) * 2048;

    f32x16 cinit;
#pragma unroll
    for (int r = 0; r < 16; ++r) cinit[r] = c0;

    // prologue: K tiles 0,1; QK[t0][0]
    bf16x8 kf[2][4];
#pragma unroll
    for (int s = 0; s < 4; ++s) kf[0][s] = load16(kb0 + s * 512 + lane * 8);
#pragma unroll
    for (int s = 0; s < 4; ++s) kf[1][s] = load16(kb0 + 2048 + s * 512 + lane * 8);
    f32x16 sa0 = cinit, sa1;
#pragma unroll
    for (int s = 0; s < 4; ++s) sa0 = mfma32(kf[0][s], qf[0][s], sa0);

#pragma unroll 2
    for (int jt = 0; jt < 16; ++jt) {
        const int cur = jt & 1, nxt = cur ^ 1;
        // V fragments for this jt (consumed by PV below; latency under QK issue)
        bf16x8 vf[2][2];
        const u16* vbc = vb0 + (size_t)jt * 2048;
#pragma unroll
        for (int db = 0; db < 2; ++db)
#pragma unroll
            for (int js = 0; js < 2; ++js)
                vf[db][js] = load16(vbc + (db * 2 + js) * 512 + lane * 8);
        // QK[t1][jt] (issue; result read one sigmoid+8 MFMAs later)
        __builtin_amdgcn_s_setprio(1);
        sa1 = cinit;
#pragma unroll
        for (int s = 0; s < 4; ++s) sa1 = mfma32(kf[cur][s], qf[1][s], sa1);
        __builtin_amdgcn_s_setprio(0);
        // prefetch K tile jt+2 into kf[cur] (consumed next iter & iter after)
        if (jt < 14) {
            const u16* kbn = kb0 + (size_t)(jt + 2) * 2048;
#pragma unroll
            for (int s = 0; s < 4; ++s) kf[cur][s] = load16(kbn + s * 512 + lane * 8);
        }
        __builtin_amdgcn_sched_barrier(0);
        // sigmoid + pack t0 (sa0 produced last iter -> no MFMA read-stall)
        bf16x8 p00, p01;
        {
            float p[16];
#pragma unroll
            for (int r = 0; r < 16; ++r) {
                float e = __builtin_amdgcn_exp2f(sa0[r]);
                p[r] = __builtin_amdgcn_rcpf(1.0f + e);
            }
            unsigned wd[8];
#pragma unroll
            for (int u2 = 0; u2 < 8; ++u2) {
                unsigned r_;
                asm("v_cvt_pk_bf16_f32 %0, %1, %2"
                    : "=v"(r_) : "v"(p[2 * u2]), "v"(p[2 * u2 + 1]));
                wd[u2] = r_;
            }
            asm("v_permlane32_swap_b32 %0, %1" : "+v"(wd[0]), "+v"(wd[2]));
            asm("v_permlane32_swap_b32 %0, %1" : "+v"(wd[1]), "+v"(wd[3]));
            asm("v_permlane32_swap_b32 %0, %1" : "+v"(wd[4]), "+v"(wd[6]));
            asm("v_permlane32_swap_b32 %0, %1" : "+v"(wd[5]), "+v"(wd[7]));
            uint4v u0 = {wd[0], wd[1], wd[2], wd[3]};
            uint4v u1 = {wd[4], wd[5], wd[6], wd[7]};
            p00 = __builtin_bit_cast(bf16x8, u0);
            p01 = __builtin_bit_cast(bf16x8, u1);
        }
        __builtin_amdgcn_sched_barrier(0);
        // PV[t0][jt] + QK[t0][jt+1] (issue)
        __builtin_amdgcn_s_setprio(1);
        accO[0][0] = mfma32(vf[0][0], p00, accO[0][0]);
        accO[0][0] = mfma32(vf[0][1], p01, accO[0][0]);
        accO[0][1] = mfma32(vf[1][0], p00, accO[0][1]);
        accO[0][1] = mfma32(vf[1][1], p01, accO[0][1]);
        if (jt < 15) {
            sa0 = cinit;
#pragma unroll
            for (int s = 0; s < 4; ++s) sa0 = mfma32(kf[nxt][s], qf[0][s], sa0);
        }
        __builtin_amdgcn_s_setprio(0);
        __builtin_amdgcn_sched_barrier(0);
        // sigmoid + pack t1 (sa1 aged by sigmoid-t0 + 8 MFMAs)
        bf16x8 p10, p11;
        {
            float p[16];
#pragma unroll
            for (int r = 0; r < 16; ++r) {
                float e = __builtin_amdgcn_exp2f(sa1[r]);
                p[r] = __builtin_amdgcn_rcpf(1.0f + e);
            }
            unsigned wd[8];
#pragma unroll
            for (int u2 = 0; u2 < 8; ++u2) {
                unsigned r_;
                asm("v_cvt_pk_bf16_f32 %0, %1, %2"
                    : "=v"(r_) : "v"(p[2 * u2]), "v"(p[2 * u2 + 1]));
                wd[u2] = r_;
            }
            asm("v_permlane32_swap_b32 %0, %1" : "+v"(wd[0]), "+v"(wd[2]));
            asm("v_permlane32_swap_b32 %0, %1" : "+v"(wd[1]), "+v"(wd[3]));
            asm("v_permlane32_swap_b32 %0, %1" : "+v"(wd[4]), "+v"(wd[6]));
            asm("v_permlane32_swap_b32 %0, %1" : "+v"(wd[5]), "+v"(wd[7]));
            uint4v u0 = {wd[0], wd[1], wd[2], wd[3]};
            uint4v u1 = {wd[4], wd[5], wd[6], wd[7]};
            p10 = __builtin_bit_cast(bf16x8, u0);
            p11 = __builtin_bit_cast(bf16x8, u1);
        }
        __builtin_amdgcn_sched_barrier(0);
        // PV[t1][jt]
        __builtin_amdgcn_s_setprio(1);
        accO[1][0] = mfma32(vf[0][0], p10, accO[1][0]);
        accO[1][0] = mfma32(vf[0][1], p11, accO[1][0]);
        accO[1][1] = mfma32(vf[1][0], p10, accO[1][1]);
        accO[1][1] = mfma32(vf[1][1], p11, accO[1][1]);
        __builtin_amdgcn_s_setprio(0);
    }

    // cross-wave combine (d = db*32 + (r&3)+8(r>>2)+4hi)
    if (jq & 1) {
#pragma unroll
        for (int t = 0; t < 2; ++t)
#pragma unroll
            for (int db = 0; db < 2; ++db)
#pragma unroll
                for (int r = 0; r < 16; ++r)
                    red[jq >> 1][t * 32 + l32][db * 32 + (r & 3) + 8 * (r >> 2) + 4 * hi] =
                        accO[t][db][r];
    }
    __syncthreads();
    if (!(jq & 1)) {
#pragma unroll
        for (int t = 0; t < 2; ++t)
#pragma unroll
            for (int db = 0; db < 2; ++db)
#pragma unroll
                for (int r = 0; r < 16; ++r)
                    accO[t][db][r] +=
                        red[jq >> 1][t * 32 + l32][db * 32 + (r & 3) + 8 * (r >> 2) + 4 * hi];
    }
    __syncthreads();
    if (jq == 2) {
#pragma unroll
        for (int t = 0; t < 2; ++t)
#pragma unroll
            for (int db = 0; db < 2; ++db)
#pragma unroll
                for (int r = 0; r < 16; ++r)
                    red[0][t * 32 + l32][db * 32 + (r & 3) + 8 * (r >> 2) + 4 * hi] =
                        accO[t][db][r];
    }
    __syncthreads();
    if (jq == 0) {
#pragma unroll
        for (int t = 0; t < 2; ++t)
#pragma unroll
            for (int db = 0; db < 2; ++db)
#pragma unroll
                for (int r = 0; r < 16; ++r)
                    accO[t][db][r] +=
                        red[0][t * 32 + l32][db * 32 + (r & 3) + 8 * (r >> 2) + 4 * hi];
#pragma unroll
        for (int t = 0; t < 2; ++t) {
            const int i = it0 * 32 + t * 32 + l32;
#pragma unroll
            for (int db = 0; db < 2; ++db)
#pragma unroll
                for (int q = 0; q < 4; ++q) {
                    int d = db * 32 + 8 * q + 4 * hi;
                    bf16x4 o4;
#pragma unroll
                    for (int r = 0; r < 4; ++r) o4[r] = (__bf16)accO[t][db][4 * q + r];
                    *(bf16x4*)&attn_out[(size_t)(b * NN + i) * 1024 + h * 64 + d] = o4;
                }
        }
    }
}

// ---------------- launch ----------------

extern "C" void kernel_launch(void* const* d_in, const int* in_sizes, int n_in,
                              void* d_out, int out_size, void* d_ws, size_t ws_size,
                              hipStream_t stream) {
    (void)in_sizes; (void)n_in; (void)out_size; (void)ws_size;
    const float* x     = (const float*)d_in[0];
    const float* Wq    = (const float*)d_in[1];
    const float* bq    = (const float*)d_in[2];
    const float* Wk    = (const float*)d_in[3];
    const float* bk    = (const float*)d_in[4];
    const float* Wv    = (const float*)d_in[5];
    const float* bv    = (const float*)d_in[6];
    const float* qn_s  = (const float*)d_in[7];
    const float* qn_b  = (const float*)d_in[8];
    const float* kn_s  = (const float*)d_in[9];
    const float* kn_b  = (const float*)d_in[10];
    const float* ib    = (const float*)d_in[11];
    const float* Wo    = (const float*)d_in[12];
    const float* bo    = (const float*)d_in[13];
    const float* gamma = (const float*)d_in[14];
    float* out = (float*)d_out;

    char* ws = (char*)d_ws;
    size_t off = 0;
    auto alloc = [&](size_t bytes) -> void* {
        void* p = ws + off;
        off += (bytes + 255) & ~(size_t)255;
        return p;
    };
    u16* xb       = (u16*)alloc((size_t)4096 * 1024 * 2);   // x bf16
    u16* wqkv_t   = (u16*)alloc((size_t)3072 * 1024 * 2);   // [n][k]
    u16* wo_t     = (u16*)alloc((size_t)1024 * 1024 * 2);
    u16* Qf       = (u16*)alloc((size_t)32 * 131072 * 2);   // fragment-linear
    u16* Kf       = (u16*)alloc((size_t)32 * 131072 * 2);
    u16* Vf       = (u16*)alloc((size_t)32 * 131072 * 2);
    u16* attn_out = (u16*)alloc((size_t)4096 * 1024 * 2);

    k_prep<<<dim3(32, 32, 5), 256, 0, stream>>>(x, Wq, Wk, Wv, Wo, xb, wqkv_t, wo_t);
    k_gemm_qkv<<<dim3(32, 24), 256, 0, stream>>>(xb, wqkv_t, bq, bk, bv,
                                                 qn_s, qn_b, kn_s, kn_b, Qf, Kf, Vf);
    k_attn<<<1024, 256, 0, stream>>>(Qf, Kf, Vf, ib, attn_out);
    k_gemm_out<<<dim3(32, 16), 256, 0, stream>>>(attn_out, wo_t, bo, gamma, out);
}